// Round 8
// baseline (2003.614 us; speedup 1.0000x reference)
//
#include <hip/hip_runtime.h>
#include <hip/hip_bf16.h>

#define NN 20000
#define IN 128
#define HH 2
#define DD 32
#define HD 64
#define KK 3
#define RR 5
#define EE 320000
#define NEG 0.2f

#define PADK 136
#define NB 313     // buckets per relation (64 dsts each)
#define NBLK 64    // partition blocks per relation
#define CHUNK 5000 // EE / NBLK
#define CAP 2048   // max edges per bucket (mean 1024, sd ~32)

typedef short v8s __attribute__((ext_vector_type(8)));
typedef float v4f __attribute__((ext_vector_type(4)));

__device__ __forceinline__ ushort f2b(float f) {
    unsigned u = __float_as_uint(f);
    unsigned r = (u + 0x7fff + ((u >> 16) & 1)) >> 16;   // RNE
    return (ushort)r;
}
__device__ __forceinline__ ushort f2h(float f) {
    _Float16 h = (_Float16)f;
    return __builtin_bit_cast(ushort, h);
}
__device__ __forceinline__ float h2f(ushort u) {
    _Float16 h = __builtin_bit_cast(_Float16, u);
    return (float)h;
}
__device__ __forceinline__ float2 up2(unsigned u) {
    return make_float2(h2f((ushort)(u & 0xFFFF)), h2f((ushort)(u >> 16)));
}

// ---------------------------------------------------------------------------
// K0a: h (fp32) -> hb (bf16) for MFMA A
// ---------------------------------------------------------------------------
__global__ __launch_bounds__(256) void cvt_h_kernel(
    const float* __restrict__ h, ushort* __restrict__ hb)
{
    int i = blockIdx.x * 256 + threadIdx.x;
    if (i >= NN * IN / 4) return;
    float4 v = ((const float4*)h)[i];
    ((ushort4*)hb)[i] = make_ushort4(f2b(v.x), f2b(v.y), f2b(v.z), f2b(v.w));
}

// ---------------------------------------------------------------------------
// K0b: weights -> wb bf16, transposed+fused: wb[r][col][k], col<64=fc else res
// ---------------------------------------------------------------------------
__global__ __launch_bounds__(256) void cvt_w_kernel(
    const float* __restrict__ fcw, const float* __restrict__ resw,
    ushort* __restrict__ wb)
{
    int i = blockIdx.x * 256 + threadIdx.x;
    if (i >= RR * 128 * IN) return;
    int k = i & 127;
    int c = (i >> 7) & 127;
    int r = i >> 14;
    float v = (c < HD) ? fcw[(r * IN + k) * HD + c] : resw[(r * IN + k) * HD + (c - HD)];
    wb[i] = f2b(v);
}

// ---------------------------------------------------------------------------
// K1: projection via bf16 MFMA; emits fp16 table t0 (x) and fp32 res.
// ---------------------------------------------------------------------------
__global__ __launch_bounds__(256) void proj_mfma(
    const ushort* __restrict__ hb, const ushort* __restrict__ wb,
    ushort* __restrict__ t0, float* __restrict__ res)
{
    __shared__ ushort As[64 * PADK];
    __shared__ ushort Bs[128 * PADK];
    int bx = blockIdx.x;
    int r = bx / 313;
    int tile = bx - r * 313;
    int n0 = tile * 64;
    int tid = threadIdx.x;

    #pragma unroll
    for (int i = 0; i < 4; i++) {
        int c = tid + 256 * i;
        int row = c >> 4;
        int off = (c & 15) * 8;
        int gn = n0 + row;
        uint4 v = make_uint4(0, 0, 0, 0);
        if (gn < NN) v = *(const uint4*)&hb[gn * IN + off];
        *(uint4*)&As[row * PADK + off] = v;
    }
    const ushort* wr = wb + (size_t)r * 128 * IN;
    #pragma unroll
    for (int i = 0; i < 8; i++) {
        int c = tid + 256 * i;
        int row = c >> 4;
        int off = (c & 15) * 8;
        *(uint4*)&Bs[row * PADK + off] = *(const uint4*)&wr[row * IN + off];
    }
    __syncthreads();

    int w = tid >> 6, lane = tid & 63;
    int lm = lane & 15, lq = lane >> 4;

    v4f acc[4][2];
    #pragma unroll
    for (int mt = 0; mt < 4; mt++)
        #pragma unroll
        for (int nt = 0; nt < 2; nt++) acc[mt][nt] = (v4f){0.f, 0.f, 0.f, 0.f};

    const ushort* Ab = &As[lm * PADK + lq * 8];
    const ushort* Bb = &Bs[(w * 32 + lm) * PADK + lq * 8];

    #pragma unroll
    for (int ks = 0; ks < 4; ks++) {
        v8s a[4], b[2];
        #pragma unroll
        for (int mt = 0; mt < 4; mt++) a[mt] = *(const v8s*)(Ab + mt * 16 * PADK + ks * 32);
        #pragma unroll
        for (int nt = 0; nt < 2; nt++) b[nt] = *(const v8s*)(Bb + nt * 16 * PADK + ks * 32);
        #pragma unroll
        for (int mt = 0; mt < 4; mt++)
            #pragma unroll
            for (int nt = 0; nt < 2; nt++)
                acc[mt][nt] = __builtin_amdgcn_mfma_f32_16x16x32_bf16(a[mt], b[nt], acc[mt][nt], 0, 0, 0);
    }

    int colbase = w * 32 + lm;
    #pragma unroll
    for (int mt = 0; mt < 4; mt++) {
        #pragma unroll
        for (int nt = 0; nt < 2; nt++) {
            int col = colbase + nt * 16;
            #pragma unroll
            for (int p = 0; p < 4; p++) {
                int node = n0 + mt * 16 + lq * 4 + p;
                if (node < NN) {
                    float v = acc[mt][nt][p];
                    if (col < HD) {
                        t0[((size_t)r * NN + node) * HD + col] = f2h(v);
                    } else {
                        res[((size_t)r * NN + node) * HD + (col - HD)] = v;
                    }
                }
            }
        }
    }
}

// ---------------------------------------------------------------------------
// K1b: per-node attention scalars el/er from fp16 t0
// ---------------------------------------------------------------------------
__global__ __launch_bounds__(256) void attn_node_kernel(
    const ushort* __restrict__ t0, const float* __restrict__ attn_l,
    const float* __restrict__ attn_r, float* __restrict__ el,
    float* __restrict__ er)
{
    int idx = blockIdx.x * 256 + threadIdx.x;
    if (idx >= RR * NN * HH) return;
    int h_ = idx & 1;
    int n = (idx >> 1) % NN;
    int r = idx / (NN * HH);
    const ushort* x = t0 + ((size_t)r * NN + n) * HD + h_ * DD;
    const float* al = attn_l + (r * HH + h_) * DD;
    const float* ar = attn_r + (r * HH + h_) * DD;
    uint4 p0 = *(const uint4*)(x);
    uint4 p1 = *(const uint4*)(x + 8);
    uint4 p2 = *(const uint4*)(x + 16);
    uint4 p3 = *(const uint4*)(x + 24);
    unsigned P[8] = {p0.x, p0.y, p0.z, p0.w, p1.x, p1.y, p1.z, p1.w};
    unsigned Q[8] = {p2.x, p2.y, p2.z, p2.w, p3.x, p3.y, p3.z, p3.w};
    float sl = 0.f, sr = 0.f;
    #pragma unroll
    for (int j = 0; j < 8; j++) {
        float2 v = up2(P[j]);
        sl += v.x * al[2 * j] + v.y * al[2 * j + 1];
        sr += v.x * ar[2 * j] + v.y * ar[2 * j + 1];
    }
    #pragma unroll
    for (int j = 0; j < 8; j++) {
        float2 v = up2(Q[j]);
        sl += v.x * al[16 + 2 * j] + v.y * al[16 + 2 * j + 1];
        sr += v.x * ar[16 + 2 * j] + v.y * ar[16 + 2 * j + 1];
    }
    el[idx] = sl;
    er[idx] = sr;
}

// ---------------------------------------------------------------------------
// A1: per-(relation, block) histogram of 313 buckets over a 5000-edge chunk.
// ---------------------------------------------------------------------------
__global__ __launch_bounds__(256) void bhist_kernel(
    const int* __restrict__ dst, int* __restrict__ blkHist)
{
    __shared__ int hh[NB];
    int r = blockIdx.x >> 6;
    int blk = blockIdx.x & 63;
    int tid = threadIdx.x;
    for (int i = tid; i < NB; i += 256) hh[i] = 0;
    __syncthreads();
    const int* D = dst + (size_t)r * EE + blk * CHUNK;
    for (int i = tid; i < CHUNK; i += 256)
        atomicAdd(&hh[D[i] >> 6], 1);
    __syncthreads();
    for (int i = tid; i < NB; i += 256)
        blkHist[((size_t)(r * NB + i)) * NBLK + blk] = hh[i];
}

// ---------------------------------------------------------------------------
// A2: per-relation exclusive scan over (bkt-major, blk-minor) matrix.
// ---------------------------------------------------------------------------
__global__ __launch_bounds__(256) void mscan_kernel(
    int* __restrict__ blkHist, int* __restrict__ bbase)
{
    __shared__ int wsum[4];
    __shared__ int carry;
    int r = blockIdx.x;
    int tid = threadIdx.x;
    int lane = tid & 63, w = tid >> 6;
    if (tid == 0) carry = 0;
    __syncthreads();
    int4* B4 = (int4*)(blkHist + (size_t)r * NB * NBLK);
    const int M4 = NB * NBLK / 4;   // 5008
    for (int base = 0; base < M4; base += 256) {
        int i4 = base + tid;
        int4 v = (i4 < M4) ? B4[i4] : make_int4(0, 0, 0, 0);
        int s = v.x + v.y + v.z + v.w;
        int x = s;
        #pragma unroll
        for (int off = 1; off < 64; off <<= 1) {
            int t = __shfl_up(x, off, 64);
            if (lane >= off) x += t;
        }
        if (lane == 63) wsum[w] = x;
        __syncthreads();
        int add = carry;
        for (int j = 0; j < w; j++) add += wsum[j];
        int px = add + x - s;
        if (i4 < M4) {
            int p0 = px, p1 = px + v.x, p2 = p1 + v.y, p3 = p2 + v.z;
            B4[i4] = make_int4(p0, p1, p2, p3);
            int e0 = i4 * 4;
            int pr[4] = {p0, p1, p2, p3};
            #pragma unroll
            for (int k = 0; k < 4; k++) {
                int e = e0 + k;
                if ((e & (NBLK - 1)) == 0) bbase[r * (NB + 1) + (e >> 6)] = pr[k];
            }
        }
        __syncthreads();
        if (tid == 255) carry += wsum[0] + wsum[1] + wsum[2] + wsum[3];
        __syncthreads();
    }
    if (tid == 0) bbase[r * (NB + 1) + NB] = EE;
}

// ---------------------------------------------------------------------------
// A3: partition scatter, LDS cursors only, exclusive global slot ranges.
// ---------------------------------------------------------------------------
__global__ __launch_bounds__(256) void bscatter_kernel(
    const int* __restrict__ src, const int* __restrict__ dst,
    const int* __restrict__ blkHist, unsigned* __restrict__ bucketRec)
{
    __shared__ int cur[NB];
    int r = blockIdx.x >> 6;
    int blk = blockIdx.x & 63;
    int tid = threadIdx.x;
    for (int i = tid; i < NB; i += 256)
        cur[i] = blkHist[((size_t)(r * NB + i)) * NBLK + blk];
    __syncthreads();
    const int* S = src + (size_t)r * EE + blk * CHUNK;
    const int* D = dst + (size_t)r * EE + blk * CHUNK;
    unsigned* BR = bucketRec + (size_t)r * EE;
    for (int i = tid; i < CHUNK; i += 256) {
        int s = S[i], d = D[i];
        int pos = atomicAdd(&cur[d >> 6], 1);
        BR[pos] = (unsigned)s | ((unsigned)(d & 63) << 15);
    }
}

// ---------------------------------------------------------------------------
// B: per-bucket LDS counting sort + exact per-dst softmax -> csrE records
// {src | dstLow<<15, half2(w0,w1)}, sequential writes.
// ---------------------------------------------------------------------------
__global__ __launch_bounds__(256) void bsort_alpha_kernel(
    const unsigned* __restrict__ bucketRec, const int* __restrict__ bbase,
    const float* __restrict__ el, const float* __restrict__ er,
    uint2* __restrict__ csrE)
{
    __shared__ int cnt64s[64];
    __shared__ int segS[65];
    __shared__ int cur[64];
    __shared__ float2 erL[64];
    __shared__ float2 mx2[64];
    __shared__ float2 inv2[64];
    __shared__ unsigned sSD[CAP];
    __shared__ float2 sL[CAP];

    int bk = blockIdx.x;
    int r = bk / NB;
    int bkt = bk - r * NB;
    int tid = threadIdx.x;
    int base = bbase[r * (NB + 1) + bkt];
    int cnt = bbase[r * (NB + 1) + bkt + 1] - base;
    if (cnt > CAP) cnt = CAP;

    if (tid < 64) {
        cnt64s[tid] = 0;
        int gn = bkt * 64 + tid;
        erL[tid] = (gn < NN) ? ((const float2*)er)[(size_t)r * NN + gn]
                             : make_float2(0.f, 0.f);
    }
    __syncthreads();
    const unsigned* BR = bucketRec + (size_t)r * EE + base;
    for (int i = tid; i < cnt; i += 256)
        atomicAdd(&cnt64s[(BR[i] >> 15) & 63], 1);
    __syncthreads();
    if (tid < 64) {
        int v = cnt64s[tid];
        int x = v;
        #pragma unroll
        for (int off = 1; off < 64; off <<= 1) {
            int tt = __shfl_up(x, off, 64);
            if (tid >= off) x += tt;
        }
        segS[tid] = x - v;
        cur[tid] = x - v;
        if (tid == 63) segS[64] = x;
    }
    __syncthreads();
    const float2* el2 = (const float2*)el + (size_t)r * NN;
    for (int i = tid; i < cnt; i += 256) {
        unsigned rec = BR[i];
        int s = rec & 0x7FFF;
        int d = (rec >> 15) & 63;
        float2 a = el2[s];
        float2 b = erL[d];
        float l0 = a.x + b.x; l0 = l0 > 0.f ? l0 : NEG * l0;
        float l1 = a.y + b.y; l1 = l1 > 0.f ? l1 : NEG * l1;
        int pos = atomicAdd(&cur[d], 1);
        sSD[pos] = rec;
        sL[pos] = make_float2(l0, l1);
    }
    __syncthreads();
    if (tid < 64) {
        int b0 = segS[tid], e0 = segS[tid + 1];
        float m0 = -1e30f, m1 = -1e30f;
        for (int i = b0; i < e0; i++) {
            float2 l = sL[i];
            m0 = fmaxf(m0, l.x); m1 = fmaxf(m1, l.y);
        }
        float s0 = 0.f, s1 = 0.f;
        for (int i = b0; i < e0; i++) {
            float2 l = sL[i];
            s0 += __expf(l.x - m0); s1 += __expf(l.y - m1);
        }
        mx2[tid] = make_float2(m0, m1);
        inv2[tid] = make_float2(1.f / fmaxf(s0, 1e-9f), 1.f / fmaxf(s1, 1e-9f));
    }
    __syncthreads();
    uint2* E = csrE + (size_t)r * EE + base;
    for (int i = tid; i < cnt; i += 256) {
        unsigned rec = sSD[i];
        int d = (rec >> 15) & 63;
        float2 l = sL[i];
        float w0 = __expf(l.x - mx2[d].x) * inv2[d].x;
        float w1 = __expf(l.y - mx2[d].y) * inv2[d].y;
        E[i] = make_uint2(rec, (unsigned)f2h(w0) | ((unsigned)f2h(w1) << 16));
    }
}

// ---------------------------------------------------------------------------
// K6: diffusion hop, PUSH mode. Block per bucket; fp32 LDS accumulator
// acc[64 dsts][64 feats]; 4 waves stream disjoint edge ranges with
// fire-and-forget ds_add atomics (no serial per-dst chain). Coalesced
// fp16 tile store at the end.
// ---------------------------------------------------------------------------
__global__ __launch_bounds__(256) void hop_kernel(
    const ushort* __restrict__ tin, ushort* __restrict__ tout,
    const uint2* __restrict__ csrE, const int* __restrict__ bbase)
{
    __shared__ float acc[64 * HD];   // 16 KB
    int bk = blockIdx.x;
    int r = bk / NB;
    int bkt = bk - r * NB;
    int tid = threadIdx.x;
    int lane = tid & 63;
    int w = tid >> 6;
    int sh = (lane >> 5) * 16;

    #pragma unroll
    for (int i = 0; i < 16; i++) acc[tid + 256 * i] = 0.f;
    __syncthreads();

    int base = bbase[r * (NB + 1) + bkt];
    int cnt  = bbase[r * (NB + 1) + bkt + 1] - base;
    const uint2* E = csrE + (size_t)r * EE + base;
    const ushort* T = tin + (size_t)r * NN * HD;

    int lo = (cnt * w) >> 2;
    int hi = (cnt * (w + 1)) >> 2;
    int i = lo;
    for (; i + 3 < hi; i += 4) {
        uint2 e0 = E[i], e1 = E[i + 1], e2 = E[i + 2], e3 = E[i + 3];
        float v0 = h2f(T[(size_t)(e0.x & 0x7FFF) * HD + lane]);
        float v1 = h2f(T[(size_t)(e1.x & 0x7FFF) * HD + lane]);
        float v2 = h2f(T[(size_t)(e2.x & 0x7FFF) * HD + lane]);
        float v3 = h2f(T[(size_t)(e3.x & 0x7FFF) * HD + lane]);
        atomicAdd(&acc[((e0.x >> 15) & 63) * HD + lane], h2f((ushort)(e0.y >> sh)) * v0);
        atomicAdd(&acc[((e1.x >> 15) & 63) * HD + lane], h2f((ushort)(e1.y >> sh)) * v1);
        atomicAdd(&acc[((e2.x >> 15) & 63) * HD + lane], h2f((ushort)(e2.y >> sh)) * v2);
        atomicAdd(&acc[((e3.x >> 15) & 63) * HD + lane], h2f((ushort)(e3.y >> sh)) * v3);
    }
    for (; i < hi; i++) {
        uint2 e0 = E[i];
        float v0 = h2f(T[(size_t)(e0.x & 0x7FFF) * HD + lane]);
        atomicAdd(&acc[((e0.x >> 15) & 63) * HD + lane], h2f((ushort)(e0.y >> sh)) * v0);
    }
    __syncthreads();

    int row = tid >> 2, cg = tid & 3;     // 64 rows x 4 groups of 16 cols
    int node = bkt * 64 + row;
    if (node < NN) {
        ushort tmp[16];
        #pragma unroll
        for (int j = 0; j < 16; j++)
            tmp[j] = f2h(acc[row * HD + cg * 16 + j]);
        ushort* dstp = tout + ((size_t)r * NN + node) * HD + cg * 16;
        *(uint4*)dstp = *(uint4*)tmp;
        *(uint4*)(dstp + 8) = *(uint4*)(tmp + 8);
    }
}

// ---------------------------------------------------------------------------
// K7: hop-norm + hop attention + residual + relation combine + head mean.
// ---------------------------------------------------------------------------
__device__ __forceinline__ float red32(float v) {
    v += __shfl_xor(v, 16, 64);
    v += __shfl_xor(v, 8, 64);
    v += __shfl_xor(v, 4, 64);
    v += __shfl_xor(v, 2, 64);
    v += __shfl_xor(v, 1, 64);
    return v;
}

__global__ __launch_bounds__(256) void final_kernel(
    const ushort* __restrict__ t0, const ushort* __restrict__ t1,
    const ushort* __restrict__ t2, const ushort* __restrict__ t3,
    const float* __restrict__ res,
    const float* __restrict__ hal, const float* __restrict__ har,
    const float* __restrict__ w_rel, const float* __restrict__ b_rel,
    float* __restrict__ out)
{
    int w = (blockIdx.x * 256 + threadIdx.x) >> 6;
    if (w >= NN) return;
    int lane = threadIdx.x & 63;
    int h_ = lane >> 5;
    int d_ = lane & 31;
    const ushort* tb[4] = {t0, t1, t2, t3};
    float acc = 0.f;
    #pragma unroll
    for (int r = 0; r < RR; r++) {
        float wr = b_rel[r];
        #pragma unroll
        for (int j = 0; j < RR; j++) wr += w_rel[r * RR + j];
        float halv = hal[(r * HH + h_) * DD + d_];
        float harv = har[(r * HH + h_) * DD + d_];
        float vn[4], lg[4];
        float hr = 0.f;
        #pragma unroll
        for (int kk = 0; kk < 4; kk++) {
            float v = h2f(tb[kk][((size_t)r * NN + w) * HD + lane]);
            float sq = red32(v * v);
            float inv = 1.f / fmaxf(sqrtf(sq), 1e-9f);
            v *= inv;
            vn[kk] = v;
            lg[kk] = red32(v * halv);
            if (kk == 0) hr = red32(v * harv);
        }
        float mx = -1e30f;
        #pragma unroll
        for (int kk = 0; kk < 4; kk++) {
            float l = lg[kk] + hr;
            l = l > 0.f ? l : NEG * l;
            lg[kk] = l;
            mx = fmaxf(mx, l);
        }
        float s = 0.f;
        #pragma unroll
        for (int kk = 0; kk < 4; kk++) { float ex = __expf(lg[kk] - mx); lg[kk] = ex; s += ex; }
        float o = 0.f;
        #pragma unroll
        for (int kk = 0; kk < 4; kk++) o += lg[kk] * vn[kk];
        o /= s;
        o += res[((size_t)r * NN + w) * HD + lane];
        acc += wr * o;
    }
    float other = __shfl_xor(acc, 32, 64);
    if (lane < 32) out[(size_t)w * DD + d_] = 0.5f * (acc + other);
}

// ---------------------------------------------------------------------------
extern "C" void kernel_launch(void* const* d_in, const int* in_sizes, int n_in,
                              void* d_out, int out_size, void* d_ws, size_t ws_size,
                              hipStream_t stream) {
    (void)in_sizes; (void)n_in; (void)out_size; (void)ws_size;
    const float* h     = (const float*)d_in[0];
    const int*   src   = (const int*)d_in[1];
    const int*   dst   = (const int*)d_in[2];
    const float* fcw   = (const float*)d_in[3];
    const float* resw  = (const float*)d_in[4];
    const float* atl   = (const float*)d_in[5];
    const float* atr   = (const float*)d_in[6];
    const float* hal   = (const float*)d_in[7];
    const float* har   = (const float*)d_in[8];
    const float* wrel  = (const float*)d_in[9];
    const float* brel  = (const float*)d_in[10];
    float* out = (float*)d_out;

    float* ws = (float*)d_ws;
    size_t off = 0;
    float* res  = ws + off;  off += (size_t)RR * NN * HD;
    float* el   = ws + off;  off += (size_t)RR * NN * HH;
    float* er   = ws + off;  off += (size_t)RR * NN * HH;
    uint2* csrE = (uint2*)(ws + off);      off += (size_t)RR * EE * 2;
    unsigned* bucketRec = (unsigned*)(ws + off); off += (size_t)RR * EE;
    ushort* t0  = (ushort*)(ws + off);     off += (size_t)RR * NN * HD / 2;
    ushort* t1  = (ushort*)(ws + off);     off += (size_t)RR * NN * HD / 2;
    ushort* t2  = (ushort*)(ws + off);     off += (size_t)RR * NN * HD / 2;
    ushort* t3  = (ushort*)(ws + off);     off += (size_t)RR * NN * HD / 2;
    ushort* hb  = (ushort*)(ws + off);     off += (size_t)NN * IN / 2;
    ushort* wb  = (ushort*)(ws + off);     off += (size_t)RR * 128 * IN / 2;
    int* blkHist = (int*)(ws + off); off += (size_t)RR * NB * NBLK;
    int* bbase  = (int*)(ws + off);  off += (size_t)RR * (NB + 1);

    cvt_h_kernel<<<(NN * IN / 4 + 255) / 256, 256, 0, stream>>>(h, hb);
    cvt_w_kernel<<<(RR * 128 * IN + 255) / 256, 256, 0, stream>>>(fcw, resw, wb);
    proj_mfma<<<313 * RR, 256, 0, stream>>>(hb, wb, t0, res);
    attn_node_kernel<<<(RR * NN * HH + 255) / 256, 256, 0, stream>>>(t0, atl, atr, el, er);
    bhist_kernel<<<RR * NBLK, 256, 0, stream>>>(dst, blkHist);
    mscan_kernel<<<RR, 256, 0, stream>>>(blkHist, bbase);
    bscatter_kernel<<<RR * NBLK, 256, 0, stream>>>(src, dst, blkHist, bucketRec);
    bsort_alpha_kernel<<<RR * NB, 256, 0, stream>>>(bucketRec, bbase, el, er, csrE);
    hop_kernel<<<RR * NB, 256, 0, stream>>>(t0, t1, csrE, bbase);
    hop_kernel<<<RR * NB, 256, 0, stream>>>(t1, t2, csrE, bbase);
    hop_kernel<<<RR * NB, 256, 0, stream>>>(t2, t3, csrE, bbase);
    final_kernel<<<NN / 4, 256, 0, stream>>>(t0, t1, t2, t3, res, hal, har, wrel, brel, out);
}

// Round 9
// 562.706 us; speedup vs baseline: 3.5607x; 3.5607x over previous
//
#include <hip/hip_runtime.h>
#include <hip/hip_bf16.h>

#define NN 20000
#define IN 128
#define HH 2
#define DD 32
#define HD 64
#define KK 3
#define RR 5
#define EE 320000
#define NEG 0.2f

#define PADK 136
#define NB 313     // buckets per relation (64 dsts each)
#define NBLK 64    // partition blocks per relation
#define CHUNK 5000 // EE / NBLK
#define CAP 2048   // max edges per bucket (mean 1024, sd ~32)
#define RPS 20004  // rowp row stride (NN+4, 16B-aligned rows; sentinel at [NN])

typedef short v8s __attribute__((ext_vector_type(8)));
typedef float v4f __attribute__((ext_vector_type(4)));

__device__ __forceinline__ ushort f2b(float f) {
    unsigned u = __float_as_uint(f);
    unsigned r = (u + 0x7fff + ((u >> 16) & 1)) >> 16;   // RNE
    return (ushort)r;
}
__device__ __forceinline__ ushort f2h(float f) {
    _Float16 h = (_Float16)f;
    return __builtin_bit_cast(ushort, h);
}
__device__ __forceinline__ float h2f(ushort u) {
    _Float16 h = __builtin_bit_cast(_Float16, u);
    return (float)h;
}
__device__ __forceinline__ float2 up2(unsigned u) {
    return make_float2(h2f((ushort)(u & 0xFFFF)), h2f((ushort)(u >> 16)));
}

// ---------------------------------------------------------------------------
// K0a: h (fp32) -> hb (bf16) for MFMA A
// ---------------------------------------------------------------------------
__global__ __launch_bounds__(256) void cvt_h_kernel(
    const float* __restrict__ h, ushort* __restrict__ hb)
{
    int i = blockIdx.x * 256 + threadIdx.x;
    if (i >= NN * IN / 4) return;
    float4 v = ((const float4*)h)[i];
    ((ushort4*)hb)[i] = make_ushort4(f2b(v.x), f2b(v.y), f2b(v.z), f2b(v.w));
}

// ---------------------------------------------------------------------------
// K0b: weights -> wb bf16, transposed+fused: wb[r][col][k], col<64=fc else res
// ---------------------------------------------------------------------------
__global__ __launch_bounds__(256) void cvt_w_kernel(
    const float* __restrict__ fcw, const float* __restrict__ resw,
    ushort* __restrict__ wb)
{
    int i = blockIdx.x * 256 + threadIdx.x;
    if (i >= RR * 128 * IN) return;
    int k = i & 127;
    int c = (i >> 7) & 127;
    int r = i >> 14;
    float v = (c < HD) ? fcw[(r * IN + k) * HD + c] : resw[(r * IN + k) * HD + (c - HD)];
    wb[i] = f2b(v);
}

// ---------------------------------------------------------------------------
// K1: projection via bf16 MFMA; emits fp16 table t0 (x) and fp32 res.
// ---------------------------------------------------------------------------
__global__ __launch_bounds__(256) void proj_mfma(
    const ushort* __restrict__ hb, const ushort* __restrict__ wb,
    ushort* __restrict__ t0, float* __restrict__ res)
{
    __shared__ ushort As[64 * PADK];
    __shared__ ushort Bs[128 * PADK];
    int bx = blockIdx.x;
    int r = bx / 313;
    int tile = bx - r * 313;
    int n0 = tile * 64;
    int tid = threadIdx.x;

    #pragma unroll
    for (int i = 0; i < 4; i++) {
        int c = tid + 256 * i;
        int row = c >> 4;
        int off = (c & 15) * 8;
        int gn = n0 + row;
        uint4 v = make_uint4(0, 0, 0, 0);
        if (gn < NN) v = *(const uint4*)&hb[gn * IN + off];
        *(uint4*)&As[row * PADK + off] = v;
    }
    const ushort* wr = wb + (size_t)r * 128 * IN;
    #pragma unroll
    for (int i = 0; i < 8; i++) {
        int c = tid + 256 * i;
        int row = c >> 4;
        int off = (c & 15) * 8;
        *(uint4*)&Bs[row * PADK + off] = *(const uint4*)&wr[row * IN + off];
    }
    __syncthreads();

    int w = tid >> 6, lane = tid & 63;
    int lm = lane & 15, lq = lane >> 4;

    v4f acc[4][2];
    #pragma unroll
    for (int mt = 0; mt < 4; mt++)
        #pragma unroll
        for (int nt = 0; nt < 2; nt++) acc[mt][nt] = (v4f){0.f, 0.f, 0.f, 0.f};

    const ushort* Ab = &As[lm * PADK + lq * 8];
    const ushort* Bb = &Bs[(w * 32 + lm) * PADK + lq * 8];

    #pragma unroll
    for (int ks = 0; ks < 4; ks++) {
        v8s a[4], b[2];
        #pragma unroll
        for (int mt = 0; mt < 4; mt++) a[mt] = *(const v8s*)(Ab + mt * 16 * PADK + ks * 32);
        #pragma unroll
        for (int nt = 0; nt < 2; nt++) b[nt] = *(const v8s*)(Bb + nt * 16 * PADK + ks * 32);
        #pragma unroll
        for (int mt = 0; mt < 4; mt++)
            #pragma unroll
            for (int nt = 0; nt < 2; nt++)
                acc[mt][nt] = __builtin_amdgcn_mfma_f32_16x16x32_bf16(a[mt], b[nt], acc[mt][nt], 0, 0, 0);
    }

    int colbase = w * 32 + lm;
    #pragma unroll
    for (int mt = 0; mt < 4; mt++) {
        #pragma unroll
        for (int nt = 0; nt < 2; nt++) {
            int col = colbase + nt * 16;
            #pragma unroll
            for (int p = 0; p < 4; p++) {
                int node = n0 + mt * 16 + lq * 4 + p;
                if (node < NN) {
                    float v = acc[mt][nt][p];
                    if (col < HD) {
                        t0[((size_t)r * NN + node) * HD + col] = f2h(v);
                    } else {
                        res[((size_t)r * NN + node) * HD + (col - HD)] = v;
                    }
                }
            }
        }
    }
}

// ---------------------------------------------------------------------------
// K1b: per-node attention scalars el/er from fp16 t0
// ---------------------------------------------------------------------------
__global__ __launch_bounds__(256) void attn_node_kernel(
    const ushort* __restrict__ t0, const float* __restrict__ attn_l,
    const float* __restrict__ attn_r, float* __restrict__ el,
    float* __restrict__ er)
{
    int idx = blockIdx.x * 256 + threadIdx.x;
    if (idx >= RR * NN * HH) return;
    int h_ = idx & 1;
    int n = (idx >> 1) % NN;
    int r = idx / (NN * HH);
    const ushort* x = t0 + ((size_t)r * NN + n) * HD + h_ * DD;
    const float* al = attn_l + (r * HH + h_) * DD;
    const float* ar = attn_r + (r * HH + h_) * DD;
    uint4 p0 = *(const uint4*)(x);
    uint4 p1 = *(const uint4*)(x + 8);
    uint4 p2 = *(const uint4*)(x + 16);
    uint4 p3 = *(const uint4*)(x + 24);
    unsigned P[8] = {p0.x, p0.y, p0.z, p0.w, p1.x, p1.y, p1.z, p1.w};
    unsigned Q[8] = {p2.x, p2.y, p2.z, p2.w, p3.x, p3.y, p3.z, p3.w};
    float sl = 0.f, sr = 0.f;
    #pragma unroll
    for (int j = 0; j < 8; j++) {
        float2 v = up2(P[j]);
        sl += v.x * al[2 * j] + v.y * al[2 * j + 1];
        sr += v.x * ar[2 * j] + v.y * ar[2 * j + 1];
    }
    #pragma unroll
    for (int j = 0; j < 8; j++) {
        float2 v = up2(Q[j]);
        sl += v.x * al[16 + 2 * j] + v.y * al[16 + 2 * j + 1];
        sr += v.x * ar[16 + 2 * j] + v.y * ar[16 + 2 * j + 1];
    }
    el[idx] = sl;
    er[idx] = sr;
}

// ---------------------------------------------------------------------------
// A1: per-(relation, block) histogram of 313 buckets over a 5000-edge chunk.
// ---------------------------------------------------------------------------
__global__ __launch_bounds__(256) void bhist_kernel(
    const int* __restrict__ dst, int* __restrict__ blkHist)
{
    __shared__ int hh[NB];
    int r = blockIdx.x >> 6;
    int blk = blockIdx.x & 63;
    int tid = threadIdx.x;
    for (int i = tid; i < NB; i += 256) hh[i] = 0;
    __syncthreads();
    const int* D = dst + (size_t)r * EE + blk * CHUNK;
    for (int i = tid; i < CHUNK; i += 256)
        atomicAdd(&hh[D[i] >> 6], 1);
    __syncthreads();
    for (int i = tid; i < NB; i += 256)
        blkHist[((size_t)(r * NB + i)) * NBLK + blk] = hh[i];
}

// ---------------------------------------------------------------------------
// A2: per-relation exclusive scan over (bkt-major, blk-minor) matrix.
// ---------------------------------------------------------------------------
__global__ __launch_bounds__(256) void mscan_kernel(
    int* __restrict__ blkHist, int* __restrict__ bbase)
{
    __shared__ int wsum[4];
    __shared__ int carry;
    int r = blockIdx.x;
    int tid = threadIdx.x;
    int lane = tid & 63, w = tid >> 6;
    if (tid == 0) carry = 0;
    __syncthreads();
    int4* B4 = (int4*)(blkHist + (size_t)r * NB * NBLK);
    const int M4 = NB * NBLK / 4;   // 5008
    for (int base = 0; base < M4; base += 256) {
        int i4 = base + tid;
        int4 v = (i4 < M4) ? B4[i4] : make_int4(0, 0, 0, 0);
        int s = v.x + v.y + v.z + v.w;
        int x = s;
        #pragma unroll
        for (int off = 1; off < 64; off <<= 1) {
            int t = __shfl_up(x, off, 64);
            if (lane >= off) x += t;
        }
        if (lane == 63) wsum[w] = x;
        __syncthreads();
        int add = carry;
        for (int j = 0; j < w; j++) add += wsum[j];
        int px = add + x - s;
        if (i4 < M4) {
            int p0 = px, p1 = px + v.x, p2 = p1 + v.y, p3 = p2 + v.z;
            B4[i4] = make_int4(p0, p1, p2, p3);
            int e0 = i4 * 4;
            int pr[4] = {p0, p1, p2, p3};
            #pragma unroll
            for (int k = 0; k < 4; k++) {
                int e = e0 + k;
                if ((e & (NBLK - 1)) == 0) bbase[r * (NB + 1) + (e >> 6)] = pr[k];
            }
        }
        __syncthreads();
        if (tid == 255) carry += wsum[0] + wsum[1] + wsum[2] + wsum[3];
        __syncthreads();
    }
    if (tid == 0) bbase[r * (NB + 1) + NB] = EE;
}

// ---------------------------------------------------------------------------
// A3: partition scatter, LDS cursors only, exclusive global slot ranges.
// ---------------------------------------------------------------------------
__global__ __launch_bounds__(256) void bscatter_kernel(
    const int* __restrict__ src, const int* __restrict__ dst,
    const int* __restrict__ blkHist, unsigned* __restrict__ bucketRec)
{
    __shared__ int cur[NB];
    int r = blockIdx.x >> 6;
    int blk = blockIdx.x & 63;
    int tid = threadIdx.x;
    for (int i = tid; i < NB; i += 256)
        cur[i] = blkHist[((size_t)(r * NB + i)) * NBLK + blk];
    __syncthreads();
    const int* S = src + (size_t)r * EE + blk * CHUNK;
    const int* D = dst + (size_t)r * EE + blk * CHUNK;
    unsigned* BR = bucketRec + (size_t)r * EE;
    for (int i = tid; i < CHUNK; i += 256) {
        int s = S[i], d = D[i];
        int pos = atomicAdd(&cur[d >> 6], 1);
        BR[pos] = (unsigned)s | ((unsigned)(d & 63) << 15);
    }
}

// ---------------------------------------------------------------------------
// B: per-bucket LDS counting sort + exact per-dst softmax -> csrE records
// {src | dstLow<<15, half2(w0,w1)} + rowp (stride RPS), sequential writes.
// ---------------------------------------------------------------------------
__global__ __launch_bounds__(256) void bsort_alpha_kernel(
    const unsigned* __restrict__ bucketRec, const int* __restrict__ bbase,
    const float* __restrict__ el, const float* __restrict__ er,
    uint2* __restrict__ csrE, int* __restrict__ rowp)
{
    __shared__ int cnt64s[64];
    __shared__ int segS[65];
    __shared__ int cur[64];
    __shared__ float2 erL[64];
    __shared__ float2 mx2[64];
    __shared__ float2 inv2[64];
    __shared__ unsigned sSD[CAP];
    __shared__ float2 sL[CAP];

    int bk = blockIdx.x;
    int r = bk / NB;
    int bkt = bk - r * NB;
    int tid = threadIdx.x;
    int base = bbase[r * (NB + 1) + bkt];
    int cnt = bbase[r * (NB + 1) + bkt + 1] - base;
    if (cnt > CAP) cnt = CAP;

    if (tid < 64) {
        cnt64s[tid] = 0;
        int gn = bkt * 64 + tid;
        erL[tid] = (gn < NN) ? ((const float2*)er)[(size_t)r * NN + gn]
                             : make_float2(0.f, 0.f);
    }
    __syncthreads();
    const unsigned* BR = bucketRec + (size_t)r * EE + base;
    for (int i = tid; i < cnt; i += 256)
        atomicAdd(&cnt64s[(BR[i] >> 15) & 63], 1);
    __syncthreads();
    if (tid < 64) {
        int v = cnt64s[tid];
        int x = v;
        #pragma unroll
        for (int off = 1; off < 64; off <<= 1) {
            int tt = __shfl_up(x, off, 64);
            if (tid >= off) x += tt;
        }
        segS[tid] = x - v;
        cur[tid] = x - v;
        if (tid == 63) segS[64] = x;
    }
    __syncthreads();
    const float2* el2 = (const float2*)el + (size_t)r * NN;
    for (int i = tid; i < cnt; i += 256) {
        unsigned rec = BR[i];
        int s = rec & 0x7FFF;
        int d = (rec >> 15) & 63;
        float2 a = el2[s];
        float2 b = erL[d];
        float l0 = a.x + b.x; l0 = l0 > 0.f ? l0 : NEG * l0;
        float l1 = a.y + b.y; l1 = l1 > 0.f ? l1 : NEG * l1;
        int pos = atomicAdd(&cur[d], 1);
        sSD[pos] = rec;
        sL[pos] = make_float2(l0, l1);
    }
    __syncthreads();
    if (tid < 64) {
        int b0 = segS[tid], e0 = segS[tid + 1];
        float m0 = -1e30f, m1 = -1e30f;
        for (int i = b0; i < e0; i++) {
            float2 l = sL[i];
            m0 = fmaxf(m0, l.x); m1 = fmaxf(m1, l.y);
        }
        float s0 = 0.f, s1 = 0.f;
        for (int i = b0; i < e0; i++) {
            float2 l = sL[i];
            s0 += __expf(l.x - m0); s1 += __expf(l.y - m1);
        }
        mx2[tid] = make_float2(m0, m1);
        inv2[tid] = make_float2(1.f / fmaxf(s0, 1e-9f), 1.f / fmaxf(s1, 1e-9f));
        int gn = bkt * 64 + tid;
        if (gn < NN) rowp[r * RPS + gn] = base + segS[tid];
    }
    if (bkt == 0 && tid == 64) rowp[r * RPS + NN] = EE;
    __syncthreads();
    uint2* E = csrE + (size_t)r * EE + base;
    for (int i = tid; i < cnt; i += 256) {
        unsigned rec = sSD[i];
        int d = (rec >> 15) & 63;
        float2 l = sL[i];
        float w0 = __expf(l.x - mx2[d].x) * inv2[d].x;
        float w1 = __expf(l.y - mx2[d].y) * inv2[d].y;
        E[i] = make_uint2(rec, (unsigned)f2h(w0) | ((unsigned)f2h(w1) << 16));
    }
}

// ---------------------------------------------------------------------------
// K6: diffusion hop, PULL mode, 4 dsts per wave. Four independent edge
// streams + accumulator chains per wave (x2 with unroll) -> 8 gathers in
// flight; ragged lengths via clamp+zero-weight (no divergence).
// ---------------------------------------------------------------------------
__global__ __launch_bounds__(256) void hop_kernel(
    const ushort* __restrict__ tin, ushort* __restrict__ tout,
    const uint2* __restrict__ csrE, const int* __restrict__ rowp)
{
    int w = (blockIdx.x * 256 + threadIdx.x) >> 6;
    if (w >= RR * NN / 4) return;
    int lane = threadIdx.x & 63;
    int sh = (lane >> 5) * 16;
    int r = w / (NN / 4);
    int n0 = (w - r * (NN / 4)) * 4;

    const int* rp = rowp + r * RPS + n0;      // 16B-aligned (RPS%4==0, n0%4==0)
    int4 bb = *(const int4*)rp;
    int e4 = rp[4];
    int b[4] = {bb.x, bb.y, bb.z, bb.w};
    int e[4] = {bb.y, bb.z, bb.w, e4};

    const ushort* T = tin + (size_t)r * NN * HD;
    const uint2* E = csrE + (size_t)r * EE;

    int last[4], maxlen = 0;
    #pragma unroll
    for (int k = 0; k < 4; k++) {
        int len = e[k] - b[k];
        maxlen = maxlen > len ? maxlen : len;
        int l = e[k] - 1;
        l = l > b[k] ? l : b[k];
        last[k] = l < (EE - 1) ? l : (EE - 1);
    }

    float acc[4] = {0.f, 0.f, 0.f, 0.f};
    #pragma unroll 2
    for (int j = 0; j < maxlen; j++) {
        #pragma unroll
        for (int k = 0; k < 4; k++) {
            int idx = b[k] + j;
            int idxc = idx < last[k] ? idx : last[k];
            uint2 rec = E[idxc];
            float wgt = (idx < e[k]) ? h2f((ushort)(rec.y >> sh)) : 0.f;
            acc[k] += wgt * h2f(T[(size_t)(rec.x & 0x7FFF) * HD + lane]);
        }
    }
    #pragma unroll
    for (int k = 0; k < 4; k++)
        tout[((size_t)r * NN + n0 + k) * HD + lane] = f2h(acc[k]);
}

// ---------------------------------------------------------------------------
// K7: hop-norm + hop attention + residual + relation combine + head mean.
// ---------------------------------------------------------------------------
__device__ __forceinline__ float red32(float v) {
    v += __shfl_xor(v, 16, 64);
    v += __shfl_xor(v, 8, 64);
    v += __shfl_xor(v, 4, 64);
    v += __shfl_xor(v, 2, 64);
    v += __shfl_xor(v, 1, 64);
    return v;
}

__global__ __launch_bounds__(256) void final_kernel(
    const ushort* __restrict__ t0, const ushort* __restrict__ t1,
    const ushort* __restrict__ t2, const ushort* __restrict__ t3,
    const float* __restrict__ res,
    const float* __restrict__ hal, const float* __restrict__ har,
    const float* __restrict__ w_rel, const float* __restrict__ b_rel,
    float* __restrict__ out)
{
    int w = (blockIdx.x * 256 + threadIdx.x) >> 6;
    if (w >= NN) return;
    int lane = threadIdx.x & 63;
    int h_ = lane >> 5;
    int d_ = lane & 31;
    const ushort* tb[4] = {t0, t1, t2, t3};
    float acc = 0.f;
    #pragma unroll
    for (int r = 0; r < RR; r++) {
        float wr = b_rel[r];
        #pragma unroll
        for (int j = 0; j < RR; j++) wr += w_rel[r * RR + j];
        float halv = hal[(r * HH + h_) * DD + d_];
        float harv = har[(r * HH + h_) * DD + d_];
        float vn[4], lg[4];
        float hr = 0.f;
        #pragma unroll
        for (int kk = 0; kk < 4; kk++) {
            float v = h2f(tb[kk][((size_t)r * NN + w) * HD + lane]);
            float sq = red32(v * v);
            float inv = 1.f / fmaxf(sqrtf(sq), 1e-9f);
            v *= inv;
            vn[kk] = v;
            lg[kk] = red32(v * halv);
            if (kk == 0) hr = red32(v * harv);
        }
        float mx = -1e30f;
        #pragma unroll
        for (int kk = 0; kk < 4; kk++) {
            float l = lg[kk] + hr;
            l = l > 0.f ? l : NEG * l;
            lg[kk] = l;
            mx = fmaxf(mx, l);
        }
        float s = 0.f;
        #pragma unroll
        for (int kk = 0; kk < 4; kk++) { float ex = __expf(lg[kk] - mx); lg[kk] = ex; s += ex; }
        float o = 0.f;
        #pragma unroll
        for (int kk = 0; kk < 4; kk++) o += lg[kk] * vn[kk];
        o /= s;
        o += res[((size_t)r * NN + w) * HD + lane];
        acc += wr * o;
    }
    float other = __shfl_xor(acc, 32, 64);
    if (lane < 32) out[(size_t)w * DD + d_] = 0.5f * (acc + other);
}

// ---------------------------------------------------------------------------
extern "C" void kernel_launch(void* const* d_in, const int* in_sizes, int n_in,
                              void* d_out, int out_size, void* d_ws, size_t ws_size,
                              hipStream_t stream) {
    (void)in_sizes; (void)n_in; (void)out_size; (void)ws_size;
    const float* h     = (const float*)d_in[0];
    const int*   src   = (const int*)d_in[1];
    const int*   dst   = (const int*)d_in[2];
    const float* fcw   = (const float*)d_in[3];
    const float* resw  = (const float*)d_in[4];
    const float* atl   = (const float*)d_in[5];
    const float* atr   = (const float*)d_in[6];
    const float* hal   = (const float*)d_in[7];
    const float* har   = (const float*)d_in[8];
    const float* wrel  = (const float*)d_in[9];
    const float* brel  = (const float*)d_in[10];
    float* out = (float*)d_out;

    float* ws = (float*)d_ws;
    size_t off = 0;
    float* res  = ws + off;  off += (size_t)RR * NN * HD;
    float* el   = ws + off;  off += (size_t)RR * NN * HH;
    float* er   = ws + off;  off += (size_t)RR * NN * HH;
    uint2* csrE = (uint2*)(ws + off);      off += (size_t)RR * EE * 2;
    unsigned* bucketRec = (unsigned*)(ws + off); off += (size_t)RR * EE;
    ushort* t0  = (ushort*)(ws + off);     off += (size_t)RR * NN * HD / 2;
    ushort* t1  = (ushort*)(ws + off);     off += (size_t)RR * NN * HD / 2;
    ushort* t2  = (ushort*)(ws + off);     off += (size_t)RR * NN * HD / 2;
    ushort* t3  = (ushort*)(ws + off);     off += (size_t)RR * NN * HD / 2;
    ushort* hb  = (ushort*)(ws + off);     off += (size_t)NN * IN / 2;
    ushort* wb  = (ushort*)(ws + off);     off += (size_t)RR * 128 * IN / 2;
    int* rowp   = (int*)(ws + off);  off += (size_t)RR * RPS;
    int* blkHist = (int*)(ws + off); off += (size_t)RR * NB * NBLK;
    int* bbase  = (int*)(ws + off);  off += (size_t)RR * (NB + 1);

    cvt_h_kernel<<<(NN * IN / 4 + 255) / 256, 256, 0, stream>>>(h, hb);
    cvt_w_kernel<<<(RR * 128 * IN + 255) / 256, 256, 0, stream>>>(fcw, resw, wb);
    proj_mfma<<<313 * RR, 256, 0, stream>>>(hb, wb, t0, res);
    attn_node_kernel<<<(RR * NN * HH + 255) / 256, 256, 0, stream>>>(t0, atl, atr, el, er);
    bhist_kernel<<<RR * NBLK, 256, 0, stream>>>(dst, blkHist);
    mscan_kernel<<<RR, 256, 0, stream>>>(blkHist, bbase);
    bscatter_kernel<<<RR * NBLK, 256, 0, stream>>>(src, dst, blkHist, bucketRec);
    bsort_alpha_kernel<<<RR * NB, 256, 0, stream>>>(bucketRec, bbase, el, er, csrE, rowp);
    hop_kernel<<<(RR * NN / 4 + 3) / 4, 256, 0, stream>>>(t0, t1, csrE, rowp);
    hop_kernel<<<(RR * NN / 4 + 3) / 4, 256, 0, stream>>>(t1, t2, csrE, rowp);
    hop_kernel<<<(RR * NN / 4 + 3) / 4, 256, 0, stream>>>(t2, t3, csrE, rowp);
    final_kernel<<<NN / 4, 256, 0, stream>>>(t0, t1, t2, t3, res, hal, har, wrel, brel, out);
}

// Round 10
// 363.169 us; speedup vs baseline: 5.5170x; 1.5494x over previous
//
#include <hip/hip_runtime.h>
#include <hip/hip_bf16.h>

#define NN 20000
#define IN 128
#define HH 2
#define DD 32
#define HD 64
#define KK 3
#define RR 5
#define EE 320000
#define NEG 0.2f

#define PADK 136
#define NB 313     // buckets per relation (64 dsts each)
#define NBLK 64    // partition blocks per relation
#define CHUNK 5000 // EE / NBLK
#define CAP 2048   // max edges per bucket (mean 1024, sd ~32)
#define RPS 20004  // rowp row stride (NN+4, 16B-aligned rows; sentinel at [NN])

typedef short v8s __attribute__((ext_vector_type(8)));
typedef float v4f __attribute__((ext_vector_type(4)));

__device__ __forceinline__ ushort f2b(float f) {
    unsigned u = __float_as_uint(f);
    unsigned r = (u + 0x7fff + ((u >> 16) & 1)) >> 16;   // RNE
    return (ushort)r;
}
__device__ __forceinline__ ushort f2h(float f) {
    _Float16 h = (_Float16)f;
    return __builtin_bit_cast(ushort, h);
}
__device__ __forceinline__ float h2f(ushort u) {
    _Float16 h = __builtin_bit_cast(_Float16, u);
    return (float)h;
}
__device__ __forceinline__ float2 up2(unsigned u) {
    return make_float2(h2f((ushort)(u & 0xFFFF)), h2f((ushort)(u >> 16)));
}

// ---------------------------------------------------------------------------
// K0a: h (fp32) -> hb (bf16) for MFMA A
// ---------------------------------------------------------------------------
__global__ __launch_bounds__(256) void cvt_h_kernel(
    const float* __restrict__ h, ushort* __restrict__ hb)
{
    int i = blockIdx.x * 256 + threadIdx.x;
    if (i >= NN * IN / 4) return;
    float4 v = ((const float4*)h)[i];
    ((ushort4*)hb)[i] = make_ushort4(f2b(v.x), f2b(v.y), f2b(v.z), f2b(v.w));
}

// ---------------------------------------------------------------------------
// K0b: weights -> wb bf16, transposed+fused: wb[r][col][k], col<64=fc else res
// ---------------------------------------------------------------------------
__global__ __launch_bounds__(256) void cvt_w_kernel(
    const float* __restrict__ fcw, const float* __restrict__ resw,
    ushort* __restrict__ wb)
{
    int i = blockIdx.x * 256 + threadIdx.x;
    if (i >= RR * 128 * IN) return;
    int k = i & 127;
    int c = (i >> 7) & 127;
    int r = i >> 14;
    float v = (c < HD) ? fcw[(r * IN + k) * HD + c] : resw[(r * IN + k) * HD + (c - HD)];
    wb[i] = f2b(v);
}

// ---------------------------------------------------------------------------
// K1: projection via bf16 MFMA; emits fp16 table t0 (x) and fp32 res.
// ---------------------------------------------------------------------------
__global__ __launch_bounds__(256) void proj_mfma(
    const ushort* __restrict__ hb, const ushort* __restrict__ wb,
    ushort* __restrict__ t0, float* __restrict__ res)
{
    __shared__ ushort As[64 * PADK];
    __shared__ ushort Bs[128 * PADK];
    int bx = blockIdx.x;
    int r = bx / 313;
    int tile = bx - r * 313;
    int n0 = tile * 64;
    int tid = threadIdx.x;

    #pragma unroll
    for (int i = 0; i < 4; i++) {
        int c = tid + 256 * i;
        int row = c >> 4;
        int off = (c & 15) * 8;
        int gn = n0 + row;
        uint4 v = make_uint4(0, 0, 0, 0);
        if (gn < NN) v = *(const uint4*)&hb[gn * IN + off];
        *(uint4*)&As[row * PADK + off] = v;
    }
    const ushort* wr = wb + (size_t)r * 128 * IN;
    #pragma unroll
    for (int i = 0; i < 8; i++) {
        int c = tid + 256 * i;
        int row = c >> 4;
        int off = (c & 15) * 8;
        *(uint4*)&Bs[row * PADK + off] = *(const uint4*)&wr[row * IN + off];
    }
    __syncthreads();

    int w = tid >> 6, lane = tid & 63;
    int lm = lane & 15, lq = lane >> 4;

    v4f acc[4][2];
    #pragma unroll
    for (int mt = 0; mt < 4; mt++)
        #pragma unroll
        for (int nt = 0; nt < 2; nt++) acc[mt][nt] = (v4f){0.f, 0.f, 0.f, 0.f};

    const ushort* Ab = &As[lm * PADK + lq * 8];
    const ushort* Bb = &Bs[(w * 32 + lm) * PADK + lq * 8];

    #pragma unroll
    for (int ks = 0; ks < 4; ks++) {
        v8s a[4], b[2];
        #pragma unroll
        for (int mt = 0; mt < 4; mt++) a[mt] = *(const v8s*)(Ab + mt * 16 * PADK + ks * 32);
        #pragma unroll
        for (int nt = 0; nt < 2; nt++) b[nt] = *(const v8s*)(Bb + nt * 16 * PADK + ks * 32);
        #pragma unroll
        for (int mt = 0; mt < 4; mt++)
            #pragma unroll
            for (int nt = 0; nt < 2; nt++)
                acc[mt][nt] = __builtin_amdgcn_mfma_f32_16x16x32_bf16(a[mt], b[nt], acc[mt][nt], 0, 0, 0);
    }

    int colbase = w * 32 + lm;
    #pragma unroll
    for (int mt = 0; mt < 4; mt++) {
        #pragma unroll
        for (int nt = 0; nt < 2; nt++) {
            int col = colbase + nt * 16;
            #pragma unroll
            for (int p = 0; p < 4; p++) {
                int node = n0 + mt * 16 + lq * 4 + p;
                if (node < NN) {
                    float v = acc[mt][nt][p];
                    if (col < HD) {
                        t0[((size_t)r * NN + node) * HD + col] = f2h(v);
                    } else {
                        res[((size_t)r * NN + node) * HD + (col - HD)] = v;
                    }
                }
            }
        }
    }
}

// ---------------------------------------------------------------------------
// K1b: per-node attention scalars el/er from fp16 t0
// ---------------------------------------------------------------------------
__global__ __launch_bounds__(256) void attn_node_kernel(
    const ushort* __restrict__ t0, const float* __restrict__ attn_l,
    const float* __restrict__ attn_r, float* __restrict__ el,
    float* __restrict__ er)
{
    int idx = blockIdx.x * 256 + threadIdx.x;
    if (idx >= RR * NN * HH) return;
    int h_ = idx & 1;
    int n = (idx >> 1) % NN;
    int r = idx / (NN * HH);
    const ushort* x = t0 + ((size_t)r * NN + n) * HD + h_ * DD;
    const float* al = attn_l + (r * HH + h_) * DD;
    const float* ar = attn_r + (r * HH + h_) * DD;
    uint4 p0 = *(const uint4*)(x);
    uint4 p1 = *(const uint4*)(x + 8);
    uint4 p2 = *(const uint4*)(x + 16);
    uint4 p3 = *(const uint4*)(x + 24);
    unsigned P[8] = {p0.x, p0.y, p0.z, p0.w, p1.x, p1.y, p1.z, p1.w};
    unsigned Q[8] = {p2.x, p2.y, p2.z, p2.w, p3.x, p3.y, p3.z, p3.w};
    float sl = 0.f, sr = 0.f;
    #pragma unroll
    for (int j = 0; j < 8; j++) {
        float2 v = up2(P[j]);
        sl += v.x * al[2 * j] + v.y * al[2 * j + 1];
        sr += v.x * ar[2 * j] + v.y * ar[2 * j + 1];
    }
    #pragma unroll
    for (int j = 0; j < 8; j++) {
        float2 v = up2(Q[j]);
        sl += v.x * al[16 + 2 * j] + v.y * al[16 + 2 * j + 1];
        sr += v.x * ar[16 + 2 * j] + v.y * ar[16 + 2 * j + 1];
    }
    el[idx] = sl;
    er[idx] = sr;
}

// ---------------------------------------------------------------------------
// A1: per-(relation, block) histogram of 313 buckets over a 5000-edge chunk.
// ---------------------------------------------------------------------------
__global__ __launch_bounds__(256) void bhist_kernel(
    const int* __restrict__ dst, int* __restrict__ blkHist)
{
    __shared__ int hh[NB];
    int r = blockIdx.x >> 6;
    int blk = blockIdx.x & 63;
    int tid = threadIdx.x;
    for (int i = tid; i < NB; i += 256) hh[i] = 0;
    __syncthreads();
    const int* D = dst + (size_t)r * EE + blk * CHUNK;
    for (int i = tid; i < CHUNK; i += 256)
        atomicAdd(&hh[D[i] >> 6], 1);
    __syncthreads();
    for (int i = tid; i < NB; i += 256)
        blkHist[((size_t)(r * NB + i)) * NBLK + blk] = hh[i];
}

// ---------------------------------------------------------------------------
// A2: per-relation exclusive scan over (bkt-major, blk-minor) matrix.
// ---------------------------------------------------------------------------
__global__ __launch_bounds__(256) void mscan_kernel(
    int* __restrict__ blkHist, int* __restrict__ bbase)
{
    __shared__ int wsum[4];
    __shared__ int carry;
    int r = blockIdx.x;
    int tid = threadIdx.x;
    int lane = tid & 63, w = tid >> 6;
    if (tid == 0) carry = 0;
    __syncthreads();
    int4* B4 = (int4*)(blkHist + (size_t)r * NB * NBLK);
    const int M4 = NB * NBLK / 4;   // 5008
    for (int base = 0; base < M4; base += 256) {
        int i4 = base + tid;
        int4 v = (i4 < M4) ? B4[i4] : make_int4(0, 0, 0, 0);
        int s = v.x + v.y + v.z + v.w;
        int x = s;
        #pragma unroll
        for (int off = 1; off < 64; off <<= 1) {
            int t = __shfl_up(x, off, 64);
            if (lane >= off) x += t;
        }
        if (lane == 63) wsum[w] = x;
        __syncthreads();
        int add = carry;
        for (int j = 0; j < w; j++) add += wsum[j];
        int px = add + x - s;
        if (i4 < M4) {
            int p0 = px, p1 = px + v.x, p2 = p1 + v.y, p3 = p2 + v.z;
            B4[i4] = make_int4(p0, p1, p2, p3);
            int e0 = i4 * 4;
            int pr[4] = {p0, p1, p2, p3};
            #pragma unroll
            for (int k = 0; k < 4; k++) {
                int e = e0 + k;
                if ((e & (NBLK - 1)) == 0) bbase[r * (NB + 1) + (e >> 6)] = pr[k];
            }
        }
        __syncthreads();
        if (tid == 255) carry += wsum[0] + wsum[1] + wsum[2] + wsum[3];
        __syncthreads();
    }
    if (tid == 0) bbase[r * (NB + 1) + NB] = EE;
}

// ---------------------------------------------------------------------------
// A3: partition scatter, LDS cursors only, exclusive global slot ranges.
// ---------------------------------------------------------------------------
__global__ __launch_bounds__(256) void bscatter_kernel(
    const int* __restrict__ src, const int* __restrict__ dst,
    const int* __restrict__ blkHist, unsigned* __restrict__ bucketRec)
{
    __shared__ int cur[NB];
    int r = blockIdx.x >> 6;
    int blk = blockIdx.x & 63;
    int tid = threadIdx.x;
    for (int i = tid; i < NB; i += 256)
        cur[i] = blkHist[((size_t)(r * NB + i)) * NBLK + blk];
    __syncthreads();
    const int* S = src + (size_t)r * EE + blk * CHUNK;
    const int* D = dst + (size_t)r * EE + blk * CHUNK;
    unsigned* BR = bucketRec + (size_t)r * EE;
    for (int i = tid; i < CHUNK; i += 256) {
        int s = S[i], d = D[i];
        int pos = atomicAdd(&cur[d >> 6], 1);
        BR[pos] = (unsigned)s | ((unsigned)(d & 63) << 15);
    }
}

// ---------------------------------------------------------------------------
// B: per-bucket LDS counting sort + exact per-dst softmax -> csrE records
// {src | dstLow<<15, half2(w0,w1)} + rowp (stride RPS), sequential writes.
// ---------------------------------------------------------------------------
__global__ __launch_bounds__(256) void bsort_alpha_kernel(
    const unsigned* __restrict__ bucketRec, const int* __restrict__ bbase,
    const float* __restrict__ el, const float* __restrict__ er,
    uint2* __restrict__ csrE, int* __restrict__ rowp)
{
    __shared__ int cnt64s[64];
    __shared__ int segS[65];
    __shared__ int cur[64];
    __shared__ float2 erL[64];
    __shared__ float2 mx2[64];
    __shared__ float2 inv2[64];
    __shared__ unsigned sSD[CAP];
    __shared__ float2 sL[CAP];

    int bk = blockIdx.x;
    int r = bk / NB;
    int bkt = bk - r * NB;
    int tid = threadIdx.x;
    int base = bbase[r * (NB + 1) + bkt];
    int cnt = bbase[r * (NB + 1) + bkt + 1] - base;
    if (cnt > CAP) cnt = CAP;

    if (tid < 64) {
        cnt64s[tid] = 0;
        int gn = bkt * 64 + tid;
        erL[tid] = (gn < NN) ? ((const float2*)er)[(size_t)r * NN + gn]
                             : make_float2(0.f, 0.f);
    }
    __syncthreads();
    const unsigned* BR = bucketRec + (size_t)r * EE + base;
    for (int i = tid; i < cnt; i += 256)
        atomicAdd(&cnt64s[(BR[i] >> 15) & 63], 1);
    __syncthreads();
    if (tid < 64) {
        int v = cnt64s[tid];
        int x = v;
        #pragma unroll
        for (int off = 1; off < 64; off <<= 1) {
            int tt = __shfl_up(x, off, 64);
            if (tid >= off) x += tt;
        }
        segS[tid] = x - v;
        cur[tid] = x - v;
        if (tid == 63) segS[64] = x;
    }
    __syncthreads();
    const float2* el2 = (const float2*)el + (size_t)r * NN;
    for (int i = tid; i < cnt; i += 256) {
        unsigned rec = BR[i];
        int s = rec & 0x7FFF;
        int d = (rec >> 15) & 63;
        float2 a = el2[s];
        float2 b = erL[d];
        float l0 = a.x + b.x; l0 = l0 > 0.f ? l0 : NEG * l0;
        float l1 = a.y + b.y; l1 = l1 > 0.f ? l1 : NEG * l1;
        int pos = atomicAdd(&cur[d], 1);
        sSD[pos] = rec;
        sL[pos] = make_float2(l0, l1);
    }
    __syncthreads();
    if (tid < 64) {
        int b0 = segS[tid], e0 = segS[tid + 1];
        float m0 = -1e30f, m1 = -1e30f;
        for (int i = b0; i < e0; i++) {
            float2 l = sL[i];
            m0 = fmaxf(m0, l.x); m1 = fmaxf(m1, l.y);
        }
        float s0 = 0.f, s1 = 0.f;
        for (int i = b0; i < e0; i++) {
            float2 l = sL[i];
            s0 += __expf(l.x - m0); s1 += __expf(l.y - m1);
        }
        mx2[tid] = make_float2(m0, m1);
        inv2[tid] = make_float2(1.f / fmaxf(s0, 1e-9f), 1.f / fmaxf(s1, 1e-9f));
        int gn = bkt * 64 + tid;
        if (gn < NN) rowp[r * RPS + gn] = base + segS[tid];
    }
    if (bkt == 0 && tid == 64) rowp[r * RPS + NN] = EE;
    __syncthreads();
    uint2* E = csrE + (size_t)r * EE + base;
    for (int i = tid; i < cnt; i += 256) {
        unsigned rec = sSD[i];
        int d = (rec >> 15) & 63;
        float2 l = sL[i];
        float w0 = __expf(l.x - mx2[d].x) * inv2[d].x;
        float w1 = __expf(l.y - mx2[d].y) * inv2[d].y;
        E[i] = make_uint2(rec, (unsigned)f2h(w0) | ((unsigned)f2h(w1) << 16));
    }
}

// ---------------------------------------------------------------------------
// K6: diffusion hop, PULL mode, wide-gather: 4 dsts per wave in lane groups
// of 16; each lane covers 4 features (8 B). Per iteration the wave issues
// 1 record load (group-broadcast) + 1 gather (512 B) = 2 VMEM / 4 edges.
// Ragged segments via clamp + zero weight (no divergence).
// ---------------------------------------------------------------------------
__global__ __launch_bounds__(256) void hop_kernel(
    const ushort* __restrict__ tin, ushort* __restrict__ tout,
    const uint2* __restrict__ csrE, const int* __restrict__ rowp)
{
    int w = (blockIdx.x * 256 + threadIdx.x) >> 6;
    if (w >= RR * (NN / 4)) return;
    int lane = threadIdx.x & 63;
    int g = lane >> 4;                 // dst group 0..3
    int f = (lane & 15) * 4;           // feature base 0..60
    int sh = ((lane >> 3) & 1) * 16;   // head select: f>=32 <=> bit3 of lane
    int r = w / (NN / 4);
    int n0 = (w - r * (NN / 4)) * 4;

    const int* rp = rowp + r * RPS + n0 + g;
    int bg = rp[0];
    int eg = rp[1];

    int len = eg - bg;
    int m = len;
    m = max(m, __shfl_xor(m, 16, 64));
    m = max(m, __shfl_xor(m, 32, 64));
    int last = eg - 1;
    last = last > bg ? last : bg;
    last = last < (EE - 1) ? last : (EE - 1);

    const ushort* T = tin + (size_t)r * NN * HD;
    const uint2* E = csrE + (size_t)r * EE;

    float4 acc = {0.f, 0.f, 0.f, 0.f};
    #pragma unroll 2
    for (int j = 0; j < m; j++) {
        int idx = bg + j;
        int idxc = idx < last ? idx : last;
        uint2 rec = E[idxc];                                 // group-broadcast
        float wgt = (idx < eg) ? h2f((ushort)(rec.y >> sh)) : 0.f;
        uint2 tv = *(const uint2*)&T[(size_t)(rec.x & 0x7FFF) * HD + f];
        float2 lo = up2(tv.x), hi = up2(tv.y);
        acc.x += wgt * lo.x;
        acc.y += wgt * lo.y;
        acc.z += wgt * hi.x;
        acc.w += wgt * hi.y;
    }
    ushort o[4] = {f2h(acc.x), f2h(acc.y), f2h(acc.z), f2h(acc.w)};
    *(uint2*)&tout[((size_t)r * NN + n0 + g) * HD + f] = *(uint2*)o;
}

// ---------------------------------------------------------------------------
// K7: hop-norm + hop attention + residual + relation combine + head mean.
// ---------------------------------------------------------------------------
__device__ __forceinline__ float red32(float v) {
    v += __shfl_xor(v, 16, 64);
    v += __shfl_xor(v, 8, 64);
    v += __shfl_xor(v, 4, 64);
    v += __shfl_xor(v, 2, 64);
    v += __shfl_xor(v, 1, 64);
    return v;
}

__global__ __launch_bounds__(256) void final_kernel(
    const ushort* __restrict__ t0, const ushort* __restrict__ t1,
    const ushort* __restrict__ t2, const ushort* __restrict__ t3,
    const float* __restrict__ res,
    const float* __restrict__ hal, const float* __restrict__ har,
    const float* __restrict__ w_rel, const float* __restrict__ b_rel,
    float* __restrict__ out)
{
    int w = (blockIdx.x * 256 + threadIdx.x) >> 6;
    if (w >= NN) return;
    int lane = threadIdx.x & 63;
    int h_ = lane >> 5;
    int d_ = lane & 31;
    const ushort* tb[4] = {t0, t1, t2, t3};
    float acc = 0.f;
    #pragma unroll
    for (int r = 0; r < RR; r++) {
        float wr = b_rel[r];
        #pragma unroll
        for (int j = 0; j < RR; j++) wr += w_rel[r * RR + j];
        float halv = hal[(r * HH + h_) * DD + d_];
        float harv = har[(r * HH + h_) * DD + d_];
        float vn[4], lg[4];
        float hr = 0.f;
        #pragma unroll
        for (int kk = 0; kk < 4; kk++) {
            float v = h2f(tb[kk][((size_t)r * NN + w) * HD + lane]);
            float sq = red32(v * v);
            float inv = 1.f / fmaxf(sqrtf(sq), 1e-9f);
            v *= inv;
            vn[kk] = v;
            lg[kk] = red32(v * halv);
            if (kk == 0) hr = red32(v * harv);
        }
        float mx = -1e30f;
        #pragma unroll
        for (int kk = 0; kk < 4; kk++) {
            float l = lg[kk] + hr;
            l = l > 0.f ? l : NEG * l;
            lg[kk] = l;
            mx = fmaxf(mx, l);
        }
        float s = 0.f;
        #pragma unroll
        for (int kk = 0; kk < 4; kk++) { float ex = __expf(lg[kk] - mx); lg[kk] = ex; s += ex; }
        float o = 0.f;
        #pragma unroll
        for (int kk = 0; kk < 4; kk++) o += lg[kk] * vn[kk];
        o /= s;
        o += res[((size_t)r * NN + w) * HD + lane];
        acc += wr * o;
    }
    float other = __shfl_xor(acc, 32, 64);
    if (lane < 32) out[(size_t)w * DD + d_] = 0.5f * (acc + other);
}

// ---------------------------------------------------------------------------
extern "C" void kernel_launch(void* const* d_in, const int* in_sizes, int n_in,
                              void* d_out, int out_size, void* d_ws, size_t ws_size,
                              hipStream_t stream) {
    (void)in_sizes; (void)n_in; (void)out_size; (void)ws_size;
    const float* h     = (const float*)d_in[0];
    const int*   src   = (const int*)d_in[1];
    const int*   dst   = (const int*)d_in[2];
    const float* fcw   = (const float*)d_in[3];
    const float* resw  = (const float*)d_in[4];
    const float* atl   = (const float*)d_in[5];
    const float* atr   = (const float*)d_in[6];
    const float* hal   = (const float*)d_in[7];
    const float* har   = (const float*)d_in[8];
    const float* wrel  = (const float*)d_in[9];
    const float* brel  = (const float*)d_in[10];
    float* out = (float*)d_out;

    float* ws = (float*)d_ws;
    size_t off = 0;
    float* res  = ws + off;  off += (size_t)RR * NN * HD;
    float* el   = ws + off;  off += (size_t)RR * NN * HH;
    float* er   = ws + off;  off += (size_t)RR * NN * HH;
    uint2* csrE = (uint2*)(ws + off);      off += (size_t)RR * EE * 2;
    unsigned* bucketRec = (unsigned*)(ws + off); off += (size_t)RR * EE;
    ushort* t0  = (ushort*)(ws + off);     off += (size_t)RR * NN * HD / 2;
    ushort* t1  = (ushort*)(ws + off);     off += (size_t)RR * NN * HD / 2;
    ushort* t2  = (ushort*)(ws + off);     off += (size_t)RR * NN * HD / 2;
    ushort* t3  = (ushort*)(ws + off);     off += (size_t)RR * NN * HD / 2;
    ushort* hb  = (ushort*)(ws + off);     off += (size_t)NN * IN / 2;
    ushort* wb  = (ushort*)(ws + off);     off += (size_t)RR * 128 * IN / 2;
    int* rowp   = (int*)(ws + off);  off += (size_t)RR * RPS;
    int* blkHist = (int*)(ws + off); off += (size_t)RR * NB * NBLK;
    int* bbase  = (int*)(ws + off);  off += (size_t)RR * (NB + 1);

    cvt_h_kernel<<<(NN * IN / 4 + 255) / 256, 256, 0, stream>>>(h, hb);
    cvt_w_kernel<<<(RR * 128 * IN + 255) / 256, 256, 0, stream>>>(fcw, resw, wb);
    proj_mfma<<<313 * RR, 256, 0, stream>>>(hb, wb, t0, res);
    attn_node_kernel<<<(RR * NN * HH + 255) / 256, 256, 0, stream>>>(t0, atl, atr, el, er);
    bhist_kernel<<<RR * NBLK, 256, 0, stream>>>(dst, blkHist);
    mscan_kernel<<<RR, 256, 0, stream>>>(blkHist, bbase);
    bscatter_kernel<<<RR * NBLK, 256, 0, stream>>>(src, dst, blkHist, bucketRec);
    bsort_alpha_kernel<<<RR * NB, 256, 0, stream>>>(bucketRec, bbase, el, er, csrE, rowp);
    hop_kernel<<<(RR * (NN / 4) + 3) / 4, 256, 0, stream>>>(t0, t1, csrE, rowp);
    hop_kernel<<<(RR * (NN / 4) + 3) / 4, 256, 0, stream>>>(t1, t2, csrE, rowp);
    hop_kernel<<<(RR * (NN / 4) + 3) / 4, 256, 0, stream>>>(t2, t3, csrE, rowp);
    final_kernel<<<NN / 4, 256, 0, stream>>>(t0, t1, t2, t3, res, hal, har, wrel, brel, out);
}

// Round 11
// 338.104 us; speedup vs baseline: 5.9260x; 1.0741x over previous
//
#include <hip/hip_runtime.h>
#include <hip/hip_bf16.h>

#define NN 20000
#define IN 128
#define HH 2
#define DD 32
#define HD 64
#define KK 3
#define RR 5
#define EE 320000
#define NEG 0.2f

#define PADK 136
#define NB 313     // buckets per relation (64 dsts each)
#define NBLK 64    // partition blocks per relation
#define CHUNK 5000 // EE / NBLK
#define CAP 2048   // max edges per bucket (mean 1024, sd ~32)
#define RPS 20004  // rowp row stride (NN+4, 16B-aligned rows; sentinel at [NN])

typedef short v8s __attribute__((ext_vector_type(8)));
typedef float v4f __attribute__((ext_vector_type(4)));

__device__ __forceinline__ ushort f2b(float f) {
    unsigned u = __float_as_uint(f);
    unsigned r = (u + 0x7fff + ((u >> 16) & 1)) >> 16;   // RNE
    return (ushort)r;
}
__device__ __forceinline__ ushort f2h(float f) {
    _Float16 h = (_Float16)f;
    return __builtin_bit_cast(ushort, h);
}
__device__ __forceinline__ float h2f(ushort u) {
    _Float16 h = __builtin_bit_cast(_Float16, u);
    return (float)h;
}
__device__ __forceinline__ float2 up2(unsigned u) {
    return make_float2(h2f((ushort)(u & 0xFFFF)), h2f((ushort)(u >> 16)));
}

// ---------------------------------------------------------------------------
// K0a: h (fp32) -> hb (bf16) for MFMA A
// ---------------------------------------------------------------------------
__global__ __launch_bounds__(256) void cvt_h_kernel(
    const float* __restrict__ h, ushort* __restrict__ hb)
{
    int i = blockIdx.x * 256 + threadIdx.x;
    if (i >= NN * IN / 4) return;
    float4 v = ((const float4*)h)[i];
    ((ushort4*)hb)[i] = make_ushort4(f2b(v.x), f2b(v.y), f2b(v.z), f2b(v.w));
}

// ---------------------------------------------------------------------------
// K0b: weights -> wb bf16, transposed+fused: wb[r][col][k], col<64=fc else res
// ---------------------------------------------------------------------------
__global__ __launch_bounds__(256) void cvt_w_kernel(
    const float* __restrict__ fcw, const float* __restrict__ resw,
    ushort* __restrict__ wb)
{
    int i = blockIdx.x * 256 + threadIdx.x;
    if (i >= RR * 128 * IN) return;
    int k = i & 127;
    int c = (i >> 7) & 127;
    int r = i >> 14;
    float v = (c < HD) ? fcw[(r * IN + k) * HD + c] : resw[(r * IN + k) * HD + (c - HD)];
    wb[i] = f2b(v);
}

// ---------------------------------------------------------------------------
// K1: projection via bf16 MFMA; emits fp16 table t0 (x) and fp32 res.
// ---------------------------------------------------------------------------
__global__ __launch_bounds__(256) void proj_mfma(
    const ushort* __restrict__ hb, const ushort* __restrict__ wb,
    ushort* __restrict__ t0, float* __restrict__ res)
{
    __shared__ ushort As[64 * PADK];
    __shared__ ushort Bs[128 * PADK];
    int bx = blockIdx.x;
    int r = bx / 313;
    int tile = bx - r * 313;
    int n0 = tile * 64;
    int tid = threadIdx.x;

    #pragma unroll
    for (int i = 0; i < 4; i++) {
        int c = tid + 256 * i;
        int row = c >> 4;
        int off = (c & 15) * 8;
        int gn = n0 + row;
        uint4 v = make_uint4(0, 0, 0, 0);
        if (gn < NN) v = *(const uint4*)&hb[gn * IN + off];
        *(uint4*)&As[row * PADK + off] = v;
    }
    const ushort* wr = wb + (size_t)r * 128 * IN;
    #pragma unroll
    for (int i = 0; i < 8; i++) {
        int c = tid + 256 * i;
        int row = c >> 4;
        int off = (c & 15) * 8;
        *(uint4*)&Bs[row * PADK + off] = *(const uint4*)&wr[row * IN + off];
    }
    __syncthreads();

    int w = tid >> 6, lane = tid & 63;
    int lm = lane & 15, lq = lane >> 4;

    v4f acc[4][2];
    #pragma unroll
    for (int mt = 0; mt < 4; mt++)
        #pragma unroll
        for (int nt = 0; nt < 2; nt++) acc[mt][nt] = (v4f){0.f, 0.f, 0.f, 0.f};

    const ushort* Ab = &As[lm * PADK + lq * 8];
    const ushort* Bb = &Bs[(w * 32 + lm) * PADK + lq * 8];

    #pragma unroll
    for (int ks = 0; ks < 4; ks++) {
        v8s a[4], b[2];
        #pragma unroll
        for (int mt = 0; mt < 4; mt++) a[mt] = *(const v8s*)(Ab + mt * 16 * PADK + ks * 32);
        #pragma unroll
        for (int nt = 0; nt < 2; nt++) b[nt] = *(const v8s*)(Bb + nt * 16 * PADK + ks * 32);
        #pragma unroll
        for (int mt = 0; mt < 4; mt++)
            #pragma unroll
            for (int nt = 0; nt < 2; nt++)
                acc[mt][nt] = __builtin_amdgcn_mfma_f32_16x16x32_bf16(a[mt], b[nt], acc[mt][nt], 0, 0, 0);
    }

    int colbase = w * 32 + lm;
    #pragma unroll
    for (int mt = 0; mt < 4; mt++) {
        #pragma unroll
        for (int nt = 0; nt < 2; nt++) {
            int col = colbase + nt * 16;
            #pragma unroll
            for (int p = 0; p < 4; p++) {
                int node = n0 + mt * 16 + lq * 4 + p;
                if (node < NN) {
                    float v = acc[mt][nt][p];
                    if (col < HD) {
                        t0[((size_t)r * NN + node) * HD + col] = f2h(v);
                    } else {
                        res[((size_t)r * NN + node) * HD + (col - HD)] = v;
                    }
                }
            }
        }
    }
}

// ---------------------------------------------------------------------------
// K1b: per-node attention scalars el/er from fp16 t0
// ---------------------------------------------------------------------------
__global__ __launch_bounds__(256) void attn_node_kernel(
    const ushort* __restrict__ t0, const float* __restrict__ attn_l,
    const float* __restrict__ attn_r, float* __restrict__ el,
    float* __restrict__ er)
{
    int idx = blockIdx.x * 256 + threadIdx.x;
    if (idx >= RR * NN * HH) return;
    int h_ = idx & 1;
    int n = (idx >> 1) % NN;
    int r = idx / (NN * HH);
    const ushort* x = t0 + ((size_t)r * NN + n) * HD + h_ * DD;
    const float* al = attn_l + (r * HH + h_) * DD;
    const float* ar = attn_r + (r * HH + h_) * DD;
    uint4 p0 = *(const uint4*)(x);
    uint4 p1 = *(const uint4*)(x + 8);
    uint4 p2 = *(const uint4*)(x + 16);
    uint4 p3 = *(const uint4*)(x + 24);
    unsigned P[8] = {p0.x, p0.y, p0.z, p0.w, p1.x, p1.y, p1.z, p1.w};
    unsigned Q[8] = {p2.x, p2.y, p2.z, p2.w, p3.x, p3.y, p3.z, p3.w};
    float sl = 0.f, sr = 0.f;
    #pragma unroll
    for (int j = 0; j < 8; j++) {
        float2 v = up2(P[j]);
        sl += v.x * al[2 * j] + v.y * al[2 * j + 1];
        sr += v.x * ar[2 * j] + v.y * ar[2 * j + 1];
    }
    #pragma unroll
    for (int j = 0; j < 8; j++) {
        float2 v = up2(Q[j]);
        sl += v.x * al[16 + 2 * j] + v.y * al[16 + 2 * j + 1];
        sr += v.x * ar[16 + 2 * j] + v.y * ar[16 + 2 * j + 1];
    }
    el[idx] = sl;
    er[idx] = sr;
}

// ---------------------------------------------------------------------------
// A1: per-(relation, block) histogram of 313 buckets over a 5000-edge chunk.
// ---------------------------------------------------------------------------
__global__ __launch_bounds__(256) void bhist_kernel(
    const int* __restrict__ dst, int* __restrict__ blkHist)
{
    __shared__ int hh[NB];
    int r = blockIdx.x >> 6;
    int blk = blockIdx.x & 63;
    int tid = threadIdx.x;
    for (int i = tid; i < NB; i += 256) hh[i] = 0;
    __syncthreads();
    const int* D = dst + (size_t)r * EE + blk * CHUNK;
    for (int i = tid; i < CHUNK; i += 256)
        atomicAdd(&hh[D[i] >> 6], 1);
    __syncthreads();
    for (int i = tid; i < NB; i += 256)
        blkHist[((size_t)(r * NB + i)) * NBLK + blk] = hh[i];
}

// ---------------------------------------------------------------------------
// A2: per-relation exclusive scan over (bkt-major, blk-minor) matrix.
// ---------------------------------------------------------------------------
__global__ __launch_bounds__(256) void mscan_kernel(
    int* __restrict__ blkHist, int* __restrict__ bbase)
{
    __shared__ int wsum[4];
    __shared__ int carry;
    int r = blockIdx.x;
    int tid = threadIdx.x;
    int lane = tid & 63, w = tid >> 6;
    if (tid == 0) carry = 0;
    __syncthreads();
    int4* B4 = (int4*)(blkHist + (size_t)r * NB * NBLK);
    const int M4 = NB * NBLK / 4;   // 5008
    for (int base = 0; base < M4; base += 256) {
        int i4 = base + tid;
        int4 v = (i4 < M4) ? B4[i4] : make_int4(0, 0, 0, 0);
        int s = v.x + v.y + v.z + v.w;
        int x = s;
        #pragma unroll
        for (int off = 1; off < 64; off <<= 1) {
            int t = __shfl_up(x, off, 64);
            if (lane >= off) x += t;
        }
        if (lane == 63) wsum[w] = x;
        __syncthreads();
        int add = carry;
        for (int j = 0; j < w; j++) add += wsum[j];
        int px = add + x - s;
        if (i4 < M4) {
            int p0 = px, p1 = px + v.x, p2 = p1 + v.y, p3 = p2 + v.z;
            B4[i4] = make_int4(p0, p1, p2, p3);
            int e0 = i4 * 4;
            int pr[4] = {p0, p1, p2, p3};
            #pragma unroll
            for (int k = 0; k < 4; k++) {
                int e = e0 + k;
                if ((e & (NBLK - 1)) == 0) bbase[r * (NB + 1) + (e >> 6)] = pr[k];
            }
        }
        __syncthreads();
        if (tid == 255) carry += wsum[0] + wsum[1] + wsum[2] + wsum[3];
        __syncthreads();
    }
    if (tid == 0) bbase[r * (NB + 1) + NB] = EE;
}

// ---------------------------------------------------------------------------
// A3: partition scatter, LDS cursors only, exclusive global slot ranges.
// ---------------------------------------------------------------------------
__global__ __launch_bounds__(256) void bscatter_kernel(
    const int* __restrict__ src, const int* __restrict__ dst,
    const int* __restrict__ blkHist, unsigned* __restrict__ bucketRec)
{
    __shared__ int cur[NB];
    int r = blockIdx.x >> 6;
    int blk = blockIdx.x & 63;
    int tid = threadIdx.x;
    for (int i = tid; i < NB; i += 256)
        cur[i] = blkHist[((size_t)(r * NB + i)) * NBLK + blk];
    __syncthreads();
    const int* S = src + (size_t)r * EE + blk * CHUNK;
    const int* D = dst + (size_t)r * EE + blk * CHUNK;
    unsigned* BR = bucketRec + (size_t)r * EE;
    for (int i = tid; i < CHUNK; i += 256) {
        int s = S[i], d = D[i];
        int pos = atomicAdd(&cur[d >> 6], 1);
        BR[pos] = (unsigned)s | ((unsigned)(d & 63) << 15);
    }
}

// ---------------------------------------------------------------------------
// B: per-bucket LDS counting sort + exact per-dst softmax -> csrE records
// {src | dstLow<<15, half2(w0,w1)} + rowp (stride RPS), sequential writes.
// ---------------------------------------------------------------------------
__global__ __launch_bounds__(256) void bsort_alpha_kernel(
    const unsigned* __restrict__ bucketRec, const int* __restrict__ bbase,
    const float* __restrict__ el, const float* __restrict__ er,
    uint2* __restrict__ csrE, int* __restrict__ rowp)
{
    __shared__ int cnt64s[64];
    __shared__ int segS[65];
    __shared__ int cur[64];
    __shared__ float2 erL[64];
    __shared__ float2 mx2[64];
    __shared__ float2 inv2[64];
    __shared__ unsigned sSD[CAP];
    __shared__ float2 sL[CAP];

    int bk = blockIdx.x;
    int r = bk / NB;
    int bkt = bk - r * NB;
    int tid = threadIdx.x;
    int base = bbase[r * (NB + 1) + bkt];
    int cnt = bbase[r * (NB + 1) + bkt + 1] - base;
    if (cnt > CAP) cnt = CAP;

    if (tid < 64) {
        cnt64s[tid] = 0;
        int gn = bkt * 64 + tid;
        erL[tid] = (gn < NN) ? ((const float2*)er)[(size_t)r * NN + gn]
                             : make_float2(0.f, 0.f);
    }
    __syncthreads();
    const unsigned* BR = bucketRec + (size_t)r * EE + base;
    for (int i = tid; i < cnt; i += 256)
        atomicAdd(&cnt64s[(BR[i] >> 15) & 63], 1);
    __syncthreads();
    if (tid < 64) {
        int v = cnt64s[tid];
        int x = v;
        #pragma unroll
        for (int off = 1; off < 64; off <<= 1) {
            int tt = __shfl_up(x, off, 64);
            if (tid >= off) x += tt;
        }
        segS[tid] = x - v;
        cur[tid] = x - v;
        if (tid == 63) segS[64] = x;
    }
    __syncthreads();
    const float2* el2 = (const float2*)el + (size_t)r * NN;
    for (int i = tid; i < cnt; i += 256) {
        unsigned rec = BR[i];
        int s = rec & 0x7FFF;
        int d = (rec >> 15) & 63;
        float2 a = el2[s];
        float2 b = erL[d];
        float l0 = a.x + b.x; l0 = l0 > 0.f ? l0 : NEG * l0;
        float l1 = a.y + b.y; l1 = l1 > 0.f ? l1 : NEG * l1;
        int pos = atomicAdd(&cur[d], 1);
        sSD[pos] = rec;
        sL[pos] = make_float2(l0, l1);
    }
    __syncthreads();
    if (tid < 64) {
        int b0 = segS[tid], e0 = segS[tid + 1];
        float m0 = -1e30f, m1 = -1e30f;
        for (int i = b0; i < e0; i++) {
            float2 l = sL[i];
            m0 = fmaxf(m0, l.x); m1 = fmaxf(m1, l.y);
        }
        float s0 = 0.f, s1 = 0.f;
        for (int i = b0; i < e0; i++) {
            float2 l = sL[i];
            s0 += __expf(l.x - m0); s1 += __expf(l.y - m1);
        }
        mx2[tid] = make_float2(m0, m1);
        inv2[tid] = make_float2(1.f / fmaxf(s0, 1e-9f), 1.f / fmaxf(s1, 1e-9f));
        int gn = bkt * 64 + tid;
        if (gn < NN) rowp[r * RPS + gn] = base + segS[tid];
    }
    if (bkt == 0 && tid == 64) rowp[r * RPS + NN] = EE;
    __syncthreads();
    uint2* E = csrE + (size_t)r * EE + base;
    for (int i = tid; i < cnt; i += 256) {
        unsigned rec = sSD[i];
        int d = (rec >> 15) & 63;
        float2 l = sL[i];
        float w0 = __expf(l.x - mx2[d].x) * inv2[d].x;
        float w1 = __expf(l.y - mx2[d].y) * inv2[d].y;
        E[i] = make_uint2(rec, (unsigned)f2h(w0) | ((unsigned)f2h(w1) << 16));
    }
}

// ---------------------------------------------------------------------------
// K6: diffusion hop, PULL mode, wide-gather: 4 dsts per wave in lane groups
// of 16; each lane covers 4 features (8 B). Per iteration the wave issues
// 1 record load (group-broadcast) + 1 gather (512 B) = 2 VMEM / 4 edges.
// ---------------------------------------------------------------------------
__global__ __launch_bounds__(256) void hop_kernel(
    const ushort* __restrict__ tin, ushort* __restrict__ tout,
    const uint2* __restrict__ csrE, const int* __restrict__ rowp)
{
    int w = (blockIdx.x * 256 + threadIdx.x) >> 6;
    if (w >= RR * (NN / 4)) return;
    int lane = threadIdx.x & 63;
    int g = lane >> 4;                 // dst group 0..3
    int f = (lane & 15) * 4;           // feature base 0..60
    int sh = ((lane >> 3) & 1) * 16;   // head select: f>=32 <=> bit3 of lane
    int r = w / (NN / 4);
    int n0 = (w - r * (NN / 4)) * 4;

    const int* rp = rowp + r * RPS + n0 + g;
    int bg = rp[0];
    int eg = rp[1];

    int len = eg - bg;
    int m = len;
    m = max(m, __shfl_xor(m, 16, 64));
    m = max(m, __shfl_xor(m, 32, 64));
    int last = eg - 1;
    last = last > bg ? last : bg;
    last = last < (EE - 1) ? last : (EE - 1);

    const ushort* T = tin + (size_t)r * NN * HD;
    const uint2* E = csrE + (size_t)r * EE;

    float4 acc = {0.f, 0.f, 0.f, 0.f};
    #pragma unroll 4
    for (int j = 0; j < m; j++) {
        int idx = bg + j;
        int idxc = idx < last ? idx : last;
        uint2 rec = E[idxc];                                 // group-broadcast
        float wgt = (idx < eg) ? h2f((ushort)(rec.y >> sh)) : 0.f;
        uint2 tv = *(const uint2*)&T[(size_t)(rec.x & 0x7FFF) * HD + f];
        float2 lo = up2(tv.x), hi = up2(tv.y);
        acc.x += wgt * lo.x;
        acc.y += wgt * lo.y;
        acc.z += wgt * hi.x;
        acc.w += wgt * hi.y;
    }
    ushort o[4] = {f2h(acc.x), f2h(acc.y), f2h(acc.z), f2h(acc.w)};
    *(uint2*)&tout[((size_t)r * NN + n0 + g) * HD + f] = *(uint2*)o;
}

// ---------------------------------------------------------------------------
// K7: final — thread per (node, head), NO cross-lane ops. Two-pass over fp16
// hop tables using dot(v/||v||,a) = dot(v,a)/||v||; per-head result to scratch.
// ---------------------------------------------------------------------------
__global__ __launch_bounds__(256) void final_kernel(
    const ushort* __restrict__ t0, const ushort* __restrict__ t1,
    const ushort* __restrict__ t2, const ushort* __restrict__ t3,
    const float* __restrict__ res,
    const float* __restrict__ hal, const float* __restrict__ har,
    const float* __restrict__ w_rel, const float* __restrict__ b_rel,
    float* __restrict__ scratch)
{
    int idx = blockIdx.x * 256 + threadIdx.x;
    if (idx >= NN * HH) return;
    int h_ = idx & 1;
    int n = idx >> 1;
    const ushort* tb[4] = {t0, t1, t2, t3};
    float o[DD];
    #pragma unroll
    for (int d = 0; d < DD; d++) o[d] = 0.f;

    for (int r = 0; r < RR; r++) {
        float wr = b_rel[r];
        #pragma unroll
        for (int j = 0; j < RR; j++) wr += w_rel[r * RR + j];
        float halc[DD], harc[DD];
        const float4* hp = (const float4*)(hal + (r * HH + h_) * DD);
        const float4* gp = (const float4*)(har + (r * HH + h_) * DD);
        #pragma unroll
        for (int j = 0; j < 8; j++) {
            float4 a = hp[j];
            halc[4 * j] = a.x; halc[4 * j + 1] = a.y; halc[4 * j + 2] = a.z; halc[4 * j + 3] = a.w;
            float4 b = gp[j];
            harc[4 * j] = b.x; harc[4 * j + 1] = b.y; harc[4 * j + 2] = b.z; harc[4 * j + 3] = b.w;
        }
        size_t tbase = ((size_t)r * NN + n) * HD + h_ * DD;
        float sq[4], dl[4], dr = 0.f;
        #pragma unroll
        for (int k = 0; k < 4; k++) {
            const uint2* tp = (const uint2*)(tb[k] + tbase);
            float s = 0.f, d1 = 0.f;
            #pragma unroll
            for (int j = 0; j < 8; j++) {
                uint2 q = tp[j];
                float2 v0 = up2(q.x), v1 = up2(q.y);
                s  += v0.x * v0.x + v0.y * v0.y + v1.x * v1.x + v1.y * v1.y;
                d1 += v0.x * halc[4 * j] + v0.y * halc[4 * j + 1]
                    + v1.x * halc[4 * j + 2] + v1.y * halc[4 * j + 3];
                if (k == 0)
                    dr += v0.x * harc[4 * j] + v0.y * harc[4 * j + 1]
                        + v1.x * harc[4 * j + 2] + v1.y * harc[4 * j + 3];
            }
            sq[k] = s; dl[k] = d1;
        }
        float inv[4], lg[4], mx = -1e30f;
        #pragma unroll
        for (int k = 0; k < 4; k++)
            inv[k] = 1.f / fmaxf(sqrtf(sq[k]), 1e-9f);
        #pragma unroll
        for (int k = 0; k < 4; k++) {
            float l = dl[k] * inv[k] + dr * inv[0];
            l = l > 0.f ? l : NEG * l;
            lg[k] = l;
            mx = fmaxf(mx, l);
        }
        float ssum = 0.f;
        #pragma unroll
        for (int k = 0; k < 4; k++) { lg[k] = __expf(lg[k] - mx); ssum += lg[k]; }
        float sw = wr / ssum;
        #pragma unroll
        for (int k = 0; k < 4; k++) {
            float coef = lg[k] * inv[k] * sw;
            const uint2* tp = (const uint2*)(tb[k] + tbase);
            #pragma unroll
            for (int j = 0; j < 8; j++) {
                uint2 q = tp[j];
                float2 v0 = up2(q.x), v1 = up2(q.y);
                o[4 * j]     += coef * v0.x;
                o[4 * j + 1] += coef * v0.y;
                o[4 * j + 2] += coef * v1.x;
                o[4 * j + 3] += coef * v1.y;
            }
        }
        const float4* rr = (const float4*)(res + ((size_t)r * NN + n) * HD + h_ * DD);
        #pragma unroll
        for (int j = 0; j < 8; j++) {
            float4 v = rr[j];
            o[4 * j]     += wr * v.x;
            o[4 * j + 1] += wr * v.y;
            o[4 * j + 2] += wr * v.z;
            o[4 * j + 3] += wr * v.w;
        }
    }
    float4* sp = (float4*)(scratch + (size_t)idx * DD);
    #pragma unroll
    for (int j = 0; j < 8; j++)
        sp[j] = make_float4(o[4 * j], o[4 * j + 1], o[4 * j + 2], o[4 * j + 3]);
}

// ---------------------------------------------------------------------------
// K8: head mean: out[n][d] = 0.5*(scratch[n][0][d] + scratch[n][1][d])
// ---------------------------------------------------------------------------
__global__ __launch_bounds__(256) void combine_kernel(
    const float* __restrict__ scratch, float* __restrict__ out)
{
    int i = blockIdx.x * 256 + threadIdx.x;
    if (i >= NN * DD / 4) return;
    int n = i >> 3;
    int j = i & 7;
    float4 a = ((const float4*)scratch)[n * 16 + j];
    float4 b = ((const float4*)scratch)[n * 16 + 8 + j];
    ((float4*)out)[i] = make_float4(0.5f * (a.x + b.x), 0.5f * (a.y + b.y),
                                    0.5f * (a.z + b.z), 0.5f * (a.w + b.w));
}

// ---------------------------------------------------------------------------
extern "C" void kernel_launch(void* const* d_in, const int* in_sizes, int n_in,
                              void* d_out, int out_size, void* d_ws, size_t ws_size,
                              hipStream_t stream) {
    (void)in_sizes; (void)n_in; (void)out_size; (void)ws_size;
    const float* h     = (const float*)d_in[0];
    const int*   src   = (const int*)d_in[1];
    const int*   dst   = (const int*)d_in[2];
    const float* fcw   = (const float*)d_in[3];
    const float* resw  = (const float*)d_in[4];
    const float* atl   = (const float*)d_in[5];
    const float* atr   = (const float*)d_in[6];
    const float* hal   = (const float*)d_in[7];
    const float* har   = (const float*)d_in[8];
    const float* wrel  = (const float*)d_in[9];
    const float* brel  = (const float*)d_in[10];
    float* out = (float*)d_out;

    float* ws = (float*)d_ws;
    size_t off = 0;
    float* res  = ws + off;  off += (size_t)RR * NN * HD;
    float* el   = ws + off;  off += (size_t)RR * NN * HH;
    float* er   = ws + off;  off += (size_t)RR * NN * HH;
    float* scratch = ws + off; off += (size_t)NN * HH * DD;
    uint2* csrE = (uint2*)(ws + off);      off += (size_t)RR * EE * 2;
    unsigned* bucketRec = (unsigned*)(ws + off); off += (size_t)RR * EE;
    ushort* t0  = (ushort*)(ws + off);     off += (size_t)RR * NN * HD / 2;
    ushort* t1  = (ushort*)(ws + off);     off += (size_t)RR * NN * HD / 2;
    ushort* t2  = (ushort*)(ws + off);     off += (size_t)RR * NN * HD / 2;
    ushort* t3  = (ushort*)(ws + off);     off += (size_t)RR * NN * HD / 2;
    ushort* hb  = (ushort*)(ws + off);     off += (size_t)NN * IN / 2;
    ushort* wb  = (ushort*)(ws + off);     off += (size_t)RR * 128 * IN / 2;
    int* rowp   = (int*)(ws + off);  off += (size_t)RR * RPS;
    int* blkHist = (int*)(ws + off); off += (size_t)RR * NB * NBLK;
    int* bbase  = (int*)(ws + off);  off += (size_t)RR * (NB + 1);

    cvt_h_kernel<<<(NN * IN / 4 + 255) / 256, 256, 0, stream>>>(h, hb);
    cvt_w_kernel<<<(RR * 128 * IN + 255) / 256, 256, 0, stream>>>(fcw, resw, wb);
    proj_mfma<<<313 * RR, 256, 0, stream>>>(hb, wb, t0, res);
    attn_node_kernel<<<(RR * NN * HH + 255) / 256, 256, 0, stream>>>(t0, atl, atr, el, er);
    bhist_kernel<<<RR * NBLK, 256, 0, stream>>>(dst, blkHist);
    mscan_kernel<<<RR, 256, 0, stream>>>(blkHist, bbase);
    bscatter_kernel<<<RR * NBLK, 256, 0, stream>>>(src, dst, blkHist, bucketRec);
    bsort_alpha_kernel<<<RR * NB, 256, 0, stream>>>(bucketRec, bbase, el, er, csrE, rowp);
    hop_kernel<<<(RR * (NN / 4) + 3) / 4, 256, 0, stream>>>(t0, t1, csrE, rowp);
    hop_kernel<<<(RR * (NN / 4) + 3) / 4, 256, 0, stream>>>(t1, t2, csrE, rowp);
    hop_kernel<<<(RR * (NN / 4) + 3) / 4, 256, 0, stream>>>(t2, t3, csrE, rowp);
    final_kernel<<<(NN * HH + 255) / 256, 256, 0, stream>>>(t0, t1, t2, t3, res, hal, har, wrel, brel, scratch);
    combine_kernel<<<(NN * DD / 4 + 255) / 256, 256, 0, stream>>>(scratch, out);
}

// Round 12
// 307.583 us; speedup vs baseline: 6.5141x; 1.0992x over previous
//
#include <hip/hip_runtime.h>
#include <hip/hip_bf16.h>

#define NN 20000
#define IN 128
#define HH 2
#define DD 32
#define HD 64
#define KK 3
#define RR 5
#define EE 320000
#define NEG 0.2f

#define PADK 136
#define NB 313     // buckets per relation (64 dsts each)
#define NBLK 64    // partition blocks per relation
#define CHUNK 5000 // EE / NBLK
#define CAP 2048   // max edges per bucket (mean 1024, sd ~32)
#define RPS 20004  // rowp row stride (NN+4, 16B-aligned rows; sentinel at [NN])

typedef short v8s __attribute__((ext_vector_type(8)));
typedef float v4f __attribute__((ext_vector_type(4)));

__device__ __forceinline__ ushort f2b(float f) {
    unsigned u = __float_as_uint(f);
    unsigned r = (u + 0x7fff + ((u >> 16) & 1)) >> 16;   // RNE
    return (ushort)r;
}
__device__ __forceinline__ ushort f2h(float f) {
    _Float16 h = (_Float16)f;
    return __builtin_bit_cast(ushort, h);
}
__device__ __forceinline__ float h2f(ushort u) {
    _Float16 h = __builtin_bit_cast(_Float16, u);
    return (float)h;
}
__device__ __forceinline__ float2 up2(unsigned u) {
    return make_float2(h2f((ushort)(u & 0xFFFF)), h2f((ushort)(u >> 16)));
}

// ---------------------------------------------------------------------------
// K0: fused conversions. h (fp32)->hb (bf16) and weights->wb bf16 transposed.
// ---------------------------------------------------------------------------
__global__ __launch_bounds__(256) void cvt_kernel(
    const float* __restrict__ h, ushort* __restrict__ hb,
    const float* __restrict__ fcw, const float* __restrict__ resw,
    ushort* __restrict__ wb)
{
    int i = blockIdx.x * 256 + threadIdx.x;
    const int NH4 = NN * IN / 4;           // 640000 ushort4 chunks
    if (i < NH4) {
        float4 v = ((const float4*)h)[i];
        ((ushort4*)hb)[i] = make_ushort4(f2b(v.x), f2b(v.y), f2b(v.z), f2b(v.w));
    } else {
        int j = i - NH4;
        if (j >= RR * 128 * IN) return;
        int k = j & 127;
        int c = (j >> 7) & 127;
        int r = j >> 14;
        float v = (c < HD) ? fcw[(r * IN + k) * HD + c] : resw[(r * IN + k) * HD + (c - HD)];
        wb[j] = f2b(v);
    }
}

// ---------------------------------------------------------------------------
// K1: projection via bf16 MFMA; emits fp16 table t0 (x) and fp32 res.
// ---------------------------------------------------------------------------
__global__ __launch_bounds__(256) void proj_mfma(
    const ushort* __restrict__ hb, const ushort* __restrict__ wb,
    ushort* __restrict__ t0, float* __restrict__ res)
{
    __shared__ ushort As[64 * PADK];
    __shared__ ushort Bs[128 * PADK];
    int bx = blockIdx.x;
    int r = bx / 313;
    int tile = bx - r * 313;
    int n0 = tile * 64;
    int tid = threadIdx.x;

    #pragma unroll
    for (int i = 0; i < 4; i++) {
        int c = tid + 256 * i;
        int row = c >> 4;
        int off = (c & 15) * 8;
        int gn = n0 + row;
        uint4 v = make_uint4(0, 0, 0, 0);
        if (gn < NN) v = *(const uint4*)&hb[gn * IN + off];
        *(uint4*)&As[row * PADK + off] = v;
    }
    const ushort* wr = wb + (size_t)r * 128 * IN;
    #pragma unroll
    for (int i = 0; i < 8; i++) {
        int c = tid + 256 * i;
        int row = c >> 4;
        int off = (c & 15) * 8;
        *(uint4*)&Bs[row * PADK + off] = *(const uint4*)&wr[row * IN + off];
    }
    __syncthreads();

    int w = tid >> 6, lane = tid & 63;
    int lm = lane & 15, lq = lane >> 4;

    v4f acc[4][2];
    #pragma unroll
    for (int mt = 0; mt < 4; mt++)
        #pragma unroll
        for (int nt = 0; nt < 2; nt++) acc[mt][nt] = (v4f){0.f, 0.f, 0.f, 0.f};

    const ushort* Ab = &As[lm * PADK + lq * 8];
    const ushort* Bb = &Bs[(w * 32 + lm) * PADK + lq * 8];

    #pragma unroll
    for (int ks = 0; ks < 4; ks++) {
        v8s a[4], b[2];
        #pragma unroll
        for (int mt = 0; mt < 4; mt++) a[mt] = *(const v8s*)(Ab + mt * 16 * PADK + ks * 32);
        #pragma unroll
        for (int nt = 0; nt < 2; nt++) b[nt] = *(const v8s*)(Bb + nt * 16 * PADK + ks * 32);
        #pragma unroll
        for (int mt = 0; mt < 4; mt++)
            #pragma unroll
            for (int nt = 0; nt < 2; nt++)
                acc[mt][nt] = __builtin_amdgcn_mfma_f32_16x16x32_bf16(a[mt], b[nt], acc[mt][nt], 0, 0, 0);
    }

    int colbase = w * 32 + lm;
    #pragma unroll
    for (int mt = 0; mt < 4; mt++) {
        #pragma unroll
        for (int nt = 0; nt < 2; nt++) {
            int col = colbase + nt * 16;
            #pragma unroll
            for (int p = 0; p < 4; p++) {
                int node = n0 + mt * 16 + lq * 4 + p;
                if (node < NN) {
                    float v = acc[mt][nt][p];
                    if (col < HD) {
                        t0[((size_t)r * NN + node) * HD + col] = f2h(v);
                    } else {
                        res[((size_t)r * NN + node) * HD + (col - HD)] = v;
                    }
                }
            }
        }
    }
}

// ---------------------------------------------------------------------------
// K1b: per-node attention scalars el/er from fp16 t0
// ---------------------------------------------------------------------------
__global__ __launch_bounds__(256) void attn_node_kernel(
    const ushort* __restrict__ t0, const float* __restrict__ attn_l,
    const float* __restrict__ attn_r, float* __restrict__ el,
    float* __restrict__ er)
{
    int idx = blockIdx.x * 256 + threadIdx.x;
    if (idx >= RR * NN * HH) return;
    int h_ = idx & 1;
    int n = (idx >> 1) % NN;
    int r = idx / (NN * HH);
    const ushort* x = t0 + ((size_t)r * NN + n) * HD + h_ * DD;
    const float* al = attn_l + (r * HH + h_) * DD;
    const float* ar = attn_r + (r * HH + h_) * DD;
    uint4 p0 = *(const uint4*)(x);
    uint4 p1 = *(const uint4*)(x + 8);
    uint4 p2 = *(const uint4*)(x + 16);
    uint4 p3 = *(const uint4*)(x + 24);
    unsigned P[8] = {p0.x, p0.y, p0.z, p0.w, p1.x, p1.y, p1.z, p1.w};
    unsigned Q[8] = {p2.x, p2.y, p2.z, p2.w, p3.x, p3.y, p3.z, p3.w};
    float sl = 0.f, sr = 0.f;
    #pragma unroll
    for (int j = 0; j < 8; j++) {
        float2 v = up2(P[j]);
        sl += v.x * al[2 * j] + v.y * al[2 * j + 1];
        sr += v.x * ar[2 * j] + v.y * ar[2 * j + 1];
    }
    #pragma unroll
    for (int j = 0; j < 8; j++) {
        float2 v = up2(Q[j]);
        sl += v.x * al[16 + 2 * j] + v.y * al[16 + 2 * j + 1];
        sr += v.x * ar[16 + 2 * j] + v.y * ar[16 + 2 * j + 1];
    }
    el[idx] = sl;
    er[idx] = sr;
}

// ---------------------------------------------------------------------------
// A1: per-(relation, block) histogram of 313 buckets over a 5000-edge chunk.
// ---------------------------------------------------------------------------
__global__ __launch_bounds__(256) void bhist_kernel(
    const int* __restrict__ dst, int* __restrict__ blkHist)
{
    __shared__ int hh[NB];
    int r = blockIdx.x >> 6;
    int blk = blockIdx.x & 63;
    int tid = threadIdx.x;
    for (int i = tid; i < NB; i += 256) hh[i] = 0;
    __syncthreads();
    const int* D = dst + (size_t)r * EE + blk * CHUNK;
    for (int i = tid; i < CHUNK; i += 256)
        atomicAdd(&hh[D[i] >> 6], 1);
    __syncthreads();
    for (int i = tid; i < NB; i += 256)
        blkHist[((size_t)(r * NB + i)) * NBLK + blk] = hh[i];
}

// ---------------------------------------------------------------------------
// A2: per-relation exclusive scan over (bkt-major, blk-minor) matrix.
// ---------------------------------------------------------------------------
__global__ __launch_bounds__(256) void mscan_kernel(
    int* __restrict__ blkHist, int* __restrict__ bbase)
{
    __shared__ int wsum[4];
    __shared__ int carry;
    int r = blockIdx.x;
    int tid = threadIdx.x;
    int lane = tid & 63, w = tid >> 6;
    if (tid == 0) carry = 0;
    __syncthreads();
    int4* B4 = (int4*)(blkHist + (size_t)r * NB * NBLK);
    const int M4 = NB * NBLK / 4;   // 5008
    for (int base = 0; base < M4; base += 256) {
        int i4 = base + tid;
        int4 v = (i4 < M4) ? B4[i4] : make_int4(0, 0, 0, 0);
        int s = v.x + v.y + v.z + v.w;
        int x = s;
        #pragma unroll
        for (int off = 1; off < 64; off <<= 1) {
            int t = __shfl_up(x, off, 64);
            if (lane >= off) x += t;
        }
        if (lane == 63) wsum[w] = x;
        __syncthreads();
        int add = carry;
        for (int j = 0; j < w; j++) add += wsum[j];
        int px = add + x - s;
        if (i4 < M4) {
            int p0 = px, p1 = px + v.x, p2 = p1 + v.y, p3 = p2 + v.z;
            B4[i4] = make_int4(p0, p1, p2, p3);
            int e0 = i4 * 4;
            int pr[4] = {p0, p1, p2, p3};
            #pragma unroll
            for (int k = 0; k < 4; k++) {
                int e = e0 + k;
                if ((e & (NBLK - 1)) == 0) bbase[r * (NB + 1) + (e >> 6)] = pr[k];
            }
        }
        __syncthreads();
        if (tid == 255) carry += wsum[0] + wsum[1] + wsum[2] + wsum[3];
        __syncthreads();
    }
    if (tid == 0) bbase[r * (NB + 1) + NB] = EE;
}

// ---------------------------------------------------------------------------
// A3: partition scatter, LDS cursors only, exclusive global slot ranges.
// ---------------------------------------------------------------------------
__global__ __launch_bounds__(256) void bscatter_kernel(
    const int* __restrict__ src, const int* __restrict__ dst,
    const int* __restrict__ blkHist, unsigned* __restrict__ bucketRec)
{
    __shared__ int cur[NB];
    int r = blockIdx.x >> 6;
    int blk = blockIdx.x & 63;
    int tid = threadIdx.x;
    for (int i = tid; i < NB; i += 256)
        cur[i] = blkHist[((size_t)(r * NB + i)) * NBLK + blk];
    __syncthreads();
    const int* S = src + (size_t)r * EE + blk * CHUNK;
    const int* D = dst + (size_t)r * EE + blk * CHUNK;
    unsigned* BR = bucketRec + (size_t)r * EE;
    for (int i = tid; i < CHUNK; i += 256) {
        int s = S[i], d = D[i];
        int pos = atomicAdd(&cur[d >> 6], 1);
        BR[pos] = (unsigned)s | ((unsigned)(d & 63) << 15);
    }
}

// ---------------------------------------------------------------------------
// B: per-bucket LDS counting sort + exact per-dst softmax -> csrE records
// {src | dstLow<<15, half2(w0,w1)} + rowp (stride RPS), sequential writes.
// ---------------------------------------------------------------------------
__global__ __launch_bounds__(256) void bsort_alpha_kernel(
    const unsigned* __restrict__ bucketRec, const int* __restrict__ bbase,
    const float* __restrict__ el, const float* __restrict__ er,
    uint2* __restrict__ csrE, int* __restrict__ rowp)
{
    __shared__ int cnt64s[64];
    __shared__ int segS[65];
    __shared__ int cur[64];
    __shared__ float2 erL[64];
    __shared__ float2 mx2[64];
    __shared__ float2 inv2[64];
    __shared__ unsigned sSD[CAP];
    __shared__ float2 sL[CAP];

    int bk = blockIdx.x;
    int r = bk / NB;
    int bkt = bk - r * NB;
    int tid = threadIdx.x;
    int base = bbase[r * (NB + 1) + bkt];
    int cnt = bbase[r * (NB + 1) + bkt + 1] - base;
    if (cnt > CAP) cnt = CAP;

    if (tid < 64) {
        cnt64s[tid] = 0;
        int gn = bkt * 64 + tid;
        erL[tid] = (gn < NN) ? ((const float2*)er)[(size_t)r * NN + gn]
                             : make_float2(0.f, 0.f);
    }
    __syncthreads();
    const unsigned* BR = bucketRec + (size_t)r * EE + base;
    for (int i = tid; i < cnt; i += 256)
        atomicAdd(&cnt64s[(BR[i] >> 15) & 63], 1);
    __syncthreads();
    if (tid < 64) {
        int v = cnt64s[tid];
        int x = v;
        #pragma unroll
        for (int off = 1; off < 64; off <<= 1) {
            int tt = __shfl_up(x, off, 64);
            if (tid >= off) x += tt;
        }
        segS[tid] = x - v;
        cur[tid] = x - v;
        if (tid == 63) segS[64] = x;
    }
    __syncthreads();
    const float2* el2 = (const float2*)el + (size_t)r * NN;
    for (int i = tid; i < cnt; i += 256) {
        unsigned rec = BR[i];
        int s = rec & 0x7FFF;
        int d = (rec >> 15) & 63;
        float2 a = el2[s];
        float2 b = erL[d];
        float l0 = a.x + b.x; l0 = l0 > 0.f ? l0 : NEG * l0;
        float l1 = a.y + b.y; l1 = l1 > 0.f ? l1 : NEG * l1;
        int pos = atomicAdd(&cur[d], 1);
        sSD[pos] = rec;
        sL[pos] = make_float2(l0, l1);
    }
    __syncthreads();
    if (tid < 64) {
        int b0 = segS[tid], e0 = segS[tid + 1];
        float m0 = -1e30f, m1 = -1e30f;
        for (int i = b0; i < e0; i++) {
            float2 l = sL[i];
            m0 = fmaxf(m0, l.x); m1 = fmaxf(m1, l.y);
        }
        float s0 = 0.f, s1 = 0.f;
        for (int i = b0; i < e0; i++) {
            float2 l = sL[i];
            s0 += __expf(l.x - m0); s1 += __expf(l.y - m1);
        }
        mx2[tid] = make_float2(m0, m1);
        inv2[tid] = make_float2(1.f / fmaxf(s0, 1e-9f), 1.f / fmaxf(s1, 1e-9f));
        int gn = bkt * 64 + tid;
        if (gn < NN) rowp[r * RPS + gn] = base + segS[tid];
    }
    if (bkt == 0 && tid == 64) rowp[r * RPS + NN] = EE;
    __syncthreads();
    uint2* E = csrE + (size_t)r * EE + base;
    for (int i = tid; i < cnt; i += 256) {
        unsigned rec = sSD[i];
        int d = (rec >> 15) & 63;
        float2 l = sL[i];
        float w0 = __expf(l.x - mx2[d].x) * inv2[d].x;
        float w1 = __expf(l.y - mx2[d].y) * inv2[d].y;
        E[i] = make_uint2(rec, (unsigned)f2h(w0) | ((unsigned)f2h(w1) << 16));
    }
}

// ---------------------------------------------------------------------------
// K6: diffusion hop, PULL mode, wide-gather v2: 8 dsts per wave in lane
// groups of 8; each lane covers 8 features (16 B uint4). Per iteration the
// wave issues 1 record load + 1 gather = 2 VMEM covering 8 edge-slots
// (0.25 VMEM/edge). Ragged segments via clamp + zero weight.
// ---------------------------------------------------------------------------
__global__ __launch_bounds__(256) void hop_kernel(
    const ushort* __restrict__ tin, ushort* __restrict__ tout,
    const uint2* __restrict__ csrE, const int* __restrict__ rowp)
{
    int w = (blockIdx.x * 256 + threadIdx.x) >> 6;
    if (w >= RR * (NN / 8)) return;
    int lane = threadIdx.x & 63;
    int g = lane >> 3;                 // dst group 0..7
    int f = (lane & 7) * 8;            // feature base 0..56
    int sh = ((lane >> 2) & 1) * 16;   // head select: f>=32 <=> bit2 of lane
    int r = w / (NN / 8);
    int n0 = (w - r * (NN / 8)) * 8;

    const int* rp = rowp + r * RPS + n0 + g;
    int bg = rp[0];
    int eg = rp[1];

    int m = eg - bg;
    m = max(m, __shfl_xor(m, 8, 64));
    m = max(m, __shfl_xor(m, 16, 64));
    m = max(m, __shfl_xor(m, 32, 64));
    int last = eg - 1;
    last = last > bg ? last : bg;
    last = last < (EE - 1) ? last : (EE - 1);

    const ushort* T = tin + (size_t)r * NN * HD;
    const uint2* E = csrE + (size_t)r * EE;

    float acc[8] = {0.f, 0.f, 0.f, 0.f, 0.f, 0.f, 0.f, 0.f};
    #pragma unroll 4
    for (int j = 0; j < m; j++) {
        int idx = bg + j;
        int idxc = idx < last ? idx : last;
        uint2 rec = E[idxc];                                 // group-broadcast
        float wgt = (idx < eg) ? h2f((ushort)(rec.y >> sh)) : 0.f;
        uint4 tv = *(const uint4*)&T[(size_t)(rec.x & 0x7FFF) * HD + f];
        float2 v0 = up2(tv.x), v1 = up2(tv.y), v2 = up2(tv.z), v3 = up2(tv.w);
        acc[0] += wgt * v0.x;
        acc[1] += wgt * v0.y;
        acc[2] += wgt * v1.x;
        acc[3] += wgt * v1.y;
        acc[4] += wgt * v2.x;
        acc[5] += wgt * v2.y;
        acc[6] += wgt * v3.x;
        acc[7] += wgt * v3.y;
    }
    ushort o[8];
    #pragma unroll
    for (int k = 0; k < 8; k++) o[k] = f2h(acc[k]);
    *(uint4*)&tout[((size_t)r * NN + n0 + g) * HD + f] = *(uint4*)o;
}

// ---------------------------------------------------------------------------
// K7: final — thread per (node, head), NO cross-lane ops. Two-pass over fp16
// hop tables using dot(v/||v||,a) = dot(v,a)/||v||; per-head result to scratch.
// ---------------------------------------------------------------------------
__global__ __launch_bounds__(256) void final_kernel(
    const ushort* __restrict__ t0, const ushort* __restrict__ t1,
    const ushort* __restrict__ t2, const ushort* __restrict__ t3,
    const float* __restrict__ res,
    const float* __restrict__ hal, const float* __restrict__ har,
    const float* __restrict__ w_rel, const float* __restrict__ b_rel,
    float* __restrict__ scratch)
{
    int idx = blockIdx.x * 256 + threadIdx.x;
    if (idx >= NN * HH) return;
    int h_ = idx & 1;
    int n = idx >> 1;
    const ushort* tb[4] = {t0, t1, t2, t3};
    float o[DD];
    #pragma unroll
    for (int d = 0; d < DD; d++) o[d] = 0.f;

    for (int r = 0; r < RR; r++) {
        float wr = b_rel[r];
        #pragma unroll
        for (int j = 0; j < RR; j++) wr += w_rel[r * RR + j];
        float halc[DD], harc[DD];
        const float4* hp = (const float4*)(hal + (r * HH + h_) * DD);
        const float4* gp = (const float4*)(har + (r * HH + h_) * DD);
        #pragma unroll
        for (int j = 0; j < 8; j++) {
            float4 a = hp[j];
            halc[4 * j] = a.x; halc[4 * j + 1] = a.y; halc[4 * j + 2] = a.z; halc[4 * j + 3] = a.w;
            float4 b = gp[j];
            harc[4 * j] = b.x; harc[4 * j + 1] = b.y; harc[4 * j + 2] = b.z; harc[4 * j + 3] = b.w;
        }
        size_t tbase = ((size_t)r * NN + n) * HD + h_ * DD;
        float sq[4], dl[4], dr = 0.f;
        #pragma unroll
        for (int k = 0; k < 4; k++) {
            const uint2* tp = (const uint2*)(tb[k] + tbase);
            float s = 0.f, d1 = 0.f;
            #pragma unroll
            for (int j = 0; j < 8; j++) {
                uint2 q = tp[j];
                float2 v0 = up2(q.x), v1 = up2(q.y);
                s  += v0.x * v0.x + v0.y * v0.y + v1.x * v1.x + v1.y * v1.y;
                d1 += v0.x * halc[4 * j] + v0.y * halc[4 * j + 1]
                    + v1.x * halc[4 * j + 2] + v1.y * halc[4 * j + 3];
                if (k == 0)
                    dr += v0.x * harc[4 * j] + v0.y * harc[4 * j + 1]
                        + v1.x * harc[4 * j + 2] + v1.y * harc[4 * j + 3];
            }
            sq[k] = s; dl[k] = d1;
        }
        float inv[4], lg[4], mx = -1e30f;
        #pragma unroll
        for (int k = 0; k < 4; k++)
            inv[k] = 1.f / fmaxf(sqrtf(sq[k]), 1e-9f);
        #pragma unroll
        for (int k = 0; k < 4; k++) {
            float l = dl[k] * inv[k] + dr * inv[0];
            l = l > 0.f ? l : NEG * l;
            lg[k] = l;
            mx = fmaxf(mx, l);
        }
        float ssum = 0.f;
        #pragma unroll
        for (int k = 0; k < 4; k++) { lg[k] = __expf(lg[k] - mx); ssum += lg[k]; }
        float sw = wr / ssum;
        #pragma unroll
        for (int k = 0; k < 4; k++) {
            float coef = lg[k] * inv[k] * sw;
            const uint2* tp = (const uint2*)(tb[k] + tbase);
            #pragma unroll
            for (int j = 0; j < 8; j++) {
                uint2 q = tp[j];
                float2 v0 = up2(q.x), v1 = up2(q.y);
                o[4 * j]     += coef * v0.x;
                o[4 * j + 1] += coef * v0.y;
                o[4 * j + 2] += coef * v1.x;
                o[4 * j + 3] += coef * v1.y;
            }
        }
        const float4* rr = (const float4*)(res + ((size_t)r * NN + n) * HD + h_ * DD);
        #pragma unroll
        for (int j = 0; j < 8; j++) {
            float4 v = rr[j];
            o[4 * j]     += wr * v.x;
            o[4 * j + 1] += wr * v.y;
            o[4 * j + 2] += wr * v.z;
            o[4 * j + 3] += wr * v.w;
        }
    }
    float4* sp = (float4*)(scratch + (size_t)idx * DD);
    #pragma unroll
    for (int j = 0; j < 8; j++)
        sp[j] = make_float4(o[4 * j], o[4 * j + 1], o[4 * j + 2], o[4 * j + 3]);
}

// ---------------------------------------------------------------------------
// K8: head mean: out[n][d] = 0.5*(scratch[n][0][d] + scratch[n][1][d])
// ---------------------------------------------------------------------------
__global__ __launch_bounds__(256) void combine_kernel(
    const float* __restrict__ scratch, float* __restrict__ out)
{
    int i = blockIdx.x * 256 + threadIdx.x;
    if (i >= NN * DD / 4) return;
    int n = i >> 3;
    int j = i & 7;
    float4 a = ((const float4*)scratch)[n * 16 + j];
    float4 b = ((const float4*)scratch)[n * 16 + 8 + j];
    ((float4*)out)[i] = make_float4(0.5f * (a.x + b.x), 0.5f * (a.y + b.y),
                                    0.5f * (a.z + b.z), 0.5f * (a.w + b.w));
}

// ---------------------------------------------------------------------------
extern "C" void kernel_launch(void* const* d_in, const int* in_sizes, int n_in,
                              void* d_out, int out_size, void* d_ws, size_t ws_size,
                              hipStream_t stream) {
    (void)in_sizes; (void)n_in; (void)out_size; (void)ws_size;
    const float* h     = (const float*)d_in[0];
    const int*   src   = (const int*)d_in[1];
    const int*   dst   = (const int*)d_in[2];
    const float* fcw   = (const float*)d_in[3];
    const float* resw  = (const float*)d_in[4];
    const float* atl   = (const float*)d_in[5];
    const float* atr   = (const float*)d_in[6];
    const float* hal   = (const float*)d_in[7];
    const float* har   = (const float*)d_in[8];
    const float* wrel  = (const float*)d_in[9];
    const float* brel  = (const float*)d_in[10];
    float* out = (float*)d_out;

    float* ws = (float*)d_ws;
    size_t off = 0;
    float* res  = ws + off;  off += (size_t)RR * NN * HD;
    float* el   = ws + off;  off += (size_t)RR * NN * HH;
    float* er   = ws + off;  off += (size_t)RR * NN * HH;
    float* scratch = ws + off; off += (size_t)NN * HH * DD;
    uint2* csrE = (uint2*)(ws + off);      off += (size_t)RR * EE * 2;
    unsigned* bucketRec = (unsigned*)(ws + off); off += (size_t)RR * EE;
    ushort* t0  = (ushort*)(ws + off);     off += (size_t)RR * NN * HD / 2;
    ushort* t1  = (ushort*)(ws + off);     off += (size_t)RR * NN * HD / 2;
    ushort* t2  = (ushort*)(ws + off);     off += (size_t)RR * NN * HD / 2;
    ushort* t3  = (ushort*)(ws + off);     off += (size_t)RR * NN * HD / 2;
    ushort* hb  = (ushort*)(ws + off);     off += (size_t)NN * IN / 2;
    ushort* wb  = (ushort*)(ws + off);     off += (size_t)RR * 128 * IN / 2;
    int* rowp   = (int*)(ws + off);  off += (size_t)RR * RPS;
    int* blkHist = (int*)(ws + off); off += (size_t)RR * NB * NBLK;
    int* bbase  = (int*)(ws + off);  off += (size_t)RR * (NB + 1);

    const int CVT_N = NN * IN / 4 + RR * 128 * IN;
    cvt_kernel<<<(CVT_N + 255) / 256, 256, 0, stream>>>(h, hb, fcw, resw, wb);
    proj_mfma<<<313 * RR, 256, 0, stream>>>(hb, wb, t0, res);
    attn_node_kernel<<<(RR * NN * HH + 255) / 256, 256, 0, stream>>>(t0, atl, atr, el, er);
    bhist_kernel<<<RR * NBLK, 256, 0, stream>>>(dst, blkHist);
    mscan_kernel<<<RR, 256, 0, stream>>>(blkHist, bbase);
    bscatter_kernel<<<RR * NBLK, 256, 0, stream>>>(src, dst, blkHist, bucketRec);
    bsort_alpha_kernel<<<RR * NB, 256, 0, stream>>>(bucketRec, bbase, el, er, csrE, rowp);
    hop_kernel<<<(RR * (NN / 8) + 3) / 4, 256, 0, stream>>>(t0, t1, csrE, rowp);
    hop_kernel<<<(RR * (NN / 8) + 3) / 4, 256, 0, stream>>>(t1, t2, csrE, rowp);
    hop_kernel<<<(RR * (NN / 8) + 3) / 4, 256, 0, stream>>>(t2, t3, csrE, rowp);
    final_kernel<<<(NN * HH + 255) / 256, 256, 0, stream>>>(t0, t1, t2, t3, res, hal, har, wrel, brel, scratch);
    combine_kernel<<<(NN * DD / 4 + 255) / 256, 256, 0, stream>>>(scratch, out);
}

// Round 13
// 294.129 us; speedup vs baseline: 6.8120x; 1.0457x over previous
//
#include <hip/hip_runtime.h>
#include <hip/hip_bf16.h>

#define NN 20000
#define IN 128
#define HH 2
#define DD 32
#define HD 64
#define KK 3
#define RR 5
#define EE 320000
#define NEG 0.2f

#define PADK 136
#define NB 313     // buckets per relation (64 dsts each)
#define NBLK 64    // partition blocks per relation
#define CHUNK 5000 // EE / NBLK
#define CAP 2048   // max edges per bucket (mean 1024, sd ~32)
#define RPS 20004  // rowp row stride (NN+4, 16B-aligned rows; sentinel at [NN])

typedef short v8s __attribute__((ext_vector_type(8)));
typedef float v4f __attribute__((ext_vector_type(4)));

__device__ __forceinline__ ushort f2b(float f) {
    unsigned u = __float_as_uint(f);
    unsigned r = (u + 0x7fff + ((u >> 16) & 1)) >> 16;   // RNE
    return (ushort)r;
}
__device__ __forceinline__ ushort f2h(float f) {
    _Float16 h = (_Float16)f;
    return __builtin_bit_cast(ushort, h);
}
__device__ __forceinline__ float h2f(ushort u) {
    _Float16 h = __builtin_bit_cast(_Float16, u);
    return (float)h;
}
__device__ __forceinline__ float2 up2(unsigned u) {
    return make_float2(h2f((ushort)(u & 0xFFFF)), h2f((ushort)(u >> 16)));
}

// ---------------------------------------------------------------------------
// K0: fused conversions. h (fp32)->hb (bf16) and weights->wb bf16 transposed.
// ---------------------------------------------------------------------------
__global__ __launch_bounds__(256) void cvt_kernel(
    const float* __restrict__ h, ushort* __restrict__ hb,
    const float* __restrict__ fcw, const float* __restrict__ resw,
    ushort* __restrict__ wb)
{
    int i = blockIdx.x * 256 + threadIdx.x;
    const int NH4 = NN * IN / 4;           // 640000 ushort4 chunks
    if (i < NH4) {
        float4 v = ((const float4*)h)[i];
        ((ushort4*)hb)[i] = make_ushort4(f2b(v.x), f2b(v.y), f2b(v.z), f2b(v.w));
    } else {
        int j = i - NH4;
        if (j >= RR * 128 * IN) return;
        int k = j & 127;
        int c = (j >> 7) & 127;
        int r = j >> 14;
        float v = (c < HD) ? fcw[(r * IN + k) * HD + c] : resw[(r * IN + k) * HD + (c - HD)];
        wb[j] = f2b(v);
    }
}

// ---------------------------------------------------------------------------
// K1: projection via bf16 MFMA; emits fp16 table t0 (x) and fp32 res.
// ---------------------------------------------------------------------------
__global__ __launch_bounds__(256) void proj_mfma(
    const ushort* __restrict__ hb, const ushort* __restrict__ wb,
    ushort* __restrict__ t0, float* __restrict__ res)
{
    __shared__ ushort As[64 * PADK];
    __shared__ ushort Bs[128 * PADK];
    int bx = blockIdx.x;
    int r = bx / 313;
    int tile = bx - r * 313;
    int n0 = tile * 64;
    int tid = threadIdx.x;

    #pragma unroll
    for (int i = 0; i < 4; i++) {
        int c = tid + 256 * i;
        int row = c >> 4;
        int off = (c & 15) * 8;
        int gn = n0 + row;
        uint4 v = make_uint4(0, 0, 0, 0);
        if (gn < NN) v = *(const uint4*)&hb[gn * IN + off];
        *(uint4*)&As[row * PADK + off] = v;
    }
    const ushort* wr = wb + (size_t)r * 128 * IN;
    #pragma unroll
    for (int i = 0; i < 8; i++) {
        int c = tid + 256 * i;
        int row = c >> 4;
        int off = (c & 15) * 8;
        *(uint4*)&Bs[row * PADK + off] = *(const uint4*)&wr[row * IN + off];
    }
    __syncthreads();

    int w = tid >> 6, lane = tid & 63;
    int lm = lane & 15, lq = lane >> 4;

    v4f acc[4][2];
    #pragma unroll
    for (int mt = 0; mt < 4; mt++)
        #pragma unroll
        for (int nt = 0; nt < 2; nt++) acc[mt][nt] = (v4f){0.f, 0.f, 0.f, 0.f};

    const ushort* Ab = &As[lm * PADK + lq * 8];
    const ushort* Bb = &Bs[(w * 32 + lm) * PADK + lq * 8];

    #pragma unroll
    for (int ks = 0; ks < 4; ks++) {
        v8s a[4], b[2];
        #pragma unroll
        for (int mt = 0; mt < 4; mt++) a[mt] = *(const v8s*)(Ab + mt * 16 * PADK + ks * 32);
        #pragma unroll
        for (int nt = 0; nt < 2; nt++) b[nt] = *(const v8s*)(Bb + nt * 16 * PADK + ks * 32);
        #pragma unroll
        for (int mt = 0; mt < 4; mt++)
            #pragma unroll
            for (int nt = 0; nt < 2; nt++)
                acc[mt][nt] = __builtin_amdgcn_mfma_f32_16x16x32_bf16(a[mt], b[nt], acc[mt][nt], 0, 0, 0);
    }

    int colbase = w * 32 + lm;
    #pragma unroll
    for (int mt = 0; mt < 4; mt++) {
        #pragma unroll
        for (int nt = 0; nt < 2; nt++) {
            int col = colbase + nt * 16;
            #pragma unroll
            for (int p = 0; p < 4; p++) {
                int node = n0 + mt * 16 + lq * 4 + p;
                if (node < NN) {
                    float v = acc[mt][nt][p];
                    if (col < HD) {
                        t0[((size_t)r * NN + node) * HD + col] = f2h(v);
                    } else {
                        res[((size_t)r * NN + node) * HD + (col - HD)] = v;
                    }
                }
            }
        }
    }
}

// ---------------------------------------------------------------------------
// K1b: per-node attention scalars el/er from fp16 t0
// ---------------------------------------------------------------------------
__global__ __launch_bounds__(256) void attn_node_kernel(
    const ushort* __restrict__ t0, const float* __restrict__ attn_l,
    const float* __restrict__ attn_r, float* __restrict__ el,
    float* __restrict__ er)
{
    int idx = blockIdx.x * 256 + threadIdx.x;
    if (idx >= RR * NN * HH) return;
    int h_ = idx & 1;
    int n = (idx >> 1) % NN;
    int r = idx / (NN * HH);
    const ushort* x = t0 + ((size_t)r * NN + n) * HD + h_ * DD;
    const float* al = attn_l + (r * HH + h_) * DD;
    const float* ar = attn_r + (r * HH + h_) * DD;
    uint4 p0 = *(const uint4*)(x);
    uint4 p1 = *(const uint4*)(x + 8);
    uint4 p2 = *(const uint4*)(x + 16);
    uint4 p3 = *(const uint4*)(x + 24);
    unsigned P[8] = {p0.x, p0.y, p0.z, p0.w, p1.x, p1.y, p1.z, p1.w};
    unsigned Q[8] = {p2.x, p2.y, p2.z, p2.w, p3.x, p3.y, p3.z, p3.w};
    float sl = 0.f, sr = 0.f;
    #pragma unroll
    for (int j = 0; j < 8; j++) {
        float2 v = up2(P[j]);
        sl += v.x * al[2 * j] + v.y * al[2 * j + 1];
        sr += v.x * ar[2 * j] + v.y * ar[2 * j + 1];
    }
    #pragma unroll
    for (int j = 0; j < 8; j++) {
        float2 v = up2(Q[j]);
        sl += v.x * al[16 + 2 * j] + v.y * al[16 + 2 * j + 1];
        sr += v.x * ar[16 + 2 * j] + v.y * ar[16 + 2 * j + 1];
    }
    el[idx] = sl;
    er[idx] = sr;
}

// ---------------------------------------------------------------------------
// A1: per-(relation, block) histogram of 313 buckets over a 5000-edge chunk.
// ---------------------------------------------------------------------------
__global__ __launch_bounds__(256) void bhist_kernel(
    const int* __restrict__ dst, int* __restrict__ blkHist)
{
    __shared__ int hh[NB];
    int r = blockIdx.x >> 6;
    int blk = blockIdx.x & 63;
    int tid = threadIdx.x;
    for (int i = tid; i < NB; i += 256) hh[i] = 0;
    __syncthreads();
    const int* D = dst + (size_t)r * EE + blk * CHUNK;
    for (int i = tid; i < CHUNK; i += 256)
        atomicAdd(&hh[D[i] >> 6], 1);
    __syncthreads();
    for (int i = tid; i < NB; i += 256)
        blkHist[((size_t)(r * NB + i)) * NBLK + blk] = hh[i];
}

// ---------------------------------------------------------------------------
// A2: per-relation exclusive scan over (bkt-major, blk-minor) matrix.
// ---------------------------------------------------------------------------
__global__ __launch_bounds__(256) void mscan_kernel(
    int* __restrict__ blkHist, int* __restrict__ bbase)
{
    __shared__ int wsum[4];
    __shared__ int carry;
    int r = blockIdx.x;
    int tid = threadIdx.x;
    int lane = tid & 63, w = tid >> 6;
    if (tid == 0) carry = 0;
    __syncthreads();
    int4* B4 = (int4*)(blkHist + (size_t)r * NB * NBLK);
    const int M4 = NB * NBLK / 4;   // 5008
    for (int base = 0; base < M4; base += 256) {
        int i4 = base + tid;
        int4 v = (i4 < M4) ? B4[i4] : make_int4(0, 0, 0, 0);
        int s = v.x + v.y + v.z + v.w;
        int x = s;
        #pragma unroll
        for (int off = 1; off < 64; off <<= 1) {
            int t = __shfl_up(x, off, 64);
            if (lane >= off) x += t;
        }
        if (lane == 63) wsum[w] = x;
        __syncthreads();
        int add = carry;
        for (int j = 0; j < w; j++) add += wsum[j];
        int px = add + x - s;
        if (i4 < M4) {
            int p0 = px, p1 = px + v.x, p2 = p1 + v.y, p3 = p2 + v.z;
            B4[i4] = make_int4(p0, p1, p2, p3);
            int e0 = i4 * 4;
            int pr[4] = {p0, p1, p2, p3};
            #pragma unroll
            for (int k = 0; k < 4; k++) {
                int e = e0 + k;
                if ((e & (NBLK - 1)) == 0) bbase[r * (NB + 1) + (e >> 6)] = pr[k];
            }
        }
        __syncthreads();
        if (tid == 255) carry += wsum[0] + wsum[1] + wsum[2] + wsum[3];
        __syncthreads();
    }
    if (tid == 0) bbase[r * (NB + 1) + NB] = EE;
}

// ---------------------------------------------------------------------------
// A3: partition scatter, LDS cursors only, exclusive global slot ranges.
// ---------------------------------------------------------------------------
__global__ __launch_bounds__(256) void bscatter_kernel(
    const int* __restrict__ src, const int* __restrict__ dst,
    const int* __restrict__ blkHist, unsigned* __restrict__ bucketRec)
{
    __shared__ int cur[NB];
    int r = blockIdx.x >> 6;
    int blk = blockIdx.x & 63;
    int tid = threadIdx.x;
    for (int i = tid; i < NB; i += 256)
        cur[i] = blkHist[((size_t)(r * NB + i)) * NBLK + blk];
    __syncthreads();
    const int* S = src + (size_t)r * EE + blk * CHUNK;
    const int* D = dst + (size_t)r * EE + blk * CHUNK;
    unsigned* BR = bucketRec + (size_t)r * EE;
    for (int i = tid; i < CHUNK; i += 256) {
        int s = S[i], d = D[i];
        int pos = atomicAdd(&cur[d >> 6], 1);
        BR[pos] = (unsigned)s | ((unsigned)(d & 63) << 15);
    }
}

// ---------------------------------------------------------------------------
// B: per-bucket LDS counting sort + exact per-dst softmax -> csrE records
// {src | dstLow<<15, half2(w0,w1)} + rowp (stride RPS), sequential writes.
// ---------------------------------------------------------------------------
__global__ __launch_bounds__(256) void bsort_alpha_kernel(
    const unsigned* __restrict__ bucketRec, const int* __restrict__ bbase,
    const float* __restrict__ el, const float* __restrict__ er,
    uint2* __restrict__ csrE, int* __restrict__ rowp)
{
    __shared__ int cnt64s[64];
    __shared__ int segS[65];
    __shared__ int cur[64];
    __shared__ float2 erL[64];
    __shared__ float2 mx2[64];
    __shared__ float2 inv2[64];
    __shared__ unsigned sSD[CAP];
    __shared__ float2 sL[CAP];

    int bk = blockIdx.x;
    int r = bk / NB;
    int bkt = bk - r * NB;
    int tid = threadIdx.x;
    int base = bbase[r * (NB + 1) + bkt];
    int cnt = bbase[r * (NB + 1) + bkt + 1] - base;
    if (cnt > CAP) cnt = CAP;

    if (tid < 64) {
        cnt64s[tid] = 0;
        int gn = bkt * 64 + tid;
        erL[tid] = (gn < NN) ? ((const float2*)er)[(size_t)r * NN + gn]
                             : make_float2(0.f, 0.f);
    }
    __syncthreads();
    const unsigned* BR = bucketRec + (size_t)r * EE + base;
    for (int i = tid; i < cnt; i += 256)
        atomicAdd(&cnt64s[(BR[i] >> 15) & 63], 1);
    __syncthreads();
    if (tid < 64) {
        int v = cnt64s[tid];
        int x = v;
        #pragma unroll
        for (int off = 1; off < 64; off <<= 1) {
            int tt = __shfl_up(x, off, 64);
            if (tid >= off) x += tt;
        }
        segS[tid] = x - v;
        cur[tid] = x - v;
        if (tid == 63) segS[64] = x;
    }
    __syncthreads();
    const float2* el2 = (const float2*)el + (size_t)r * NN;
    for (int i = tid; i < cnt; i += 256) {
        unsigned rec = BR[i];
        int s = rec & 0x7FFF;
        int d = (rec >> 15) & 63;
        float2 a = el2[s];
        float2 b = erL[d];
        float l0 = a.x + b.x; l0 = l0 > 0.f ? l0 : NEG * l0;
        float l1 = a.y + b.y; l1 = l1 > 0.f ? l1 : NEG * l1;
        int pos = atomicAdd(&cur[d], 1);
        sSD[pos] = rec;
        sL[pos] = make_float2(l0, l1);
    }
    __syncthreads();
    if (tid < 64) {
        int b0 = segS[tid], e0 = segS[tid + 1];
        float m0 = -1e30f, m1 = -1e30f;
        for (int i = b0; i < e0; i++) {
            float2 l = sL[i];
            m0 = fmaxf(m0, l.x); m1 = fmaxf(m1, l.y);
        }
        float s0 = 0.f, s1 = 0.f;
        for (int i = b0; i < e0; i++) {
            float2 l = sL[i];
            s0 += __expf(l.x - m0); s1 += __expf(l.y - m1);
        }
        mx2[tid] = make_float2(m0, m1);
        inv2[tid] = make_float2(1.f / fmaxf(s0, 1e-9f), 1.f / fmaxf(s1, 1e-9f));
        int gn = bkt * 64 + tid;
        if (gn < NN) rowp[r * RPS + gn] = base + segS[tid];
    }
    if (bkt == 0 && tid == 64) rowp[r * RPS + NN] = EE;
    __syncthreads();
    uint2* E = csrE + (size_t)r * EE + base;
    for (int i = tid; i < cnt; i += 256) {
        unsigned rec = sSD[i];
        int d = (rec >> 15) & 63;
        float2 l = sL[i];
        float w0 = __expf(l.x - mx2[d].x) * inv2[d].x;
        float w1 = __expf(l.y - mx2[d].y) * inv2[d].y;
        E[i] = make_uint2(rec, (unsigned)f2h(w0) | ((unsigned)f2h(w1) << 16));
    }
}

// ---------------------------------------------------------------------------
// K6: diffusion hop, PULL wide-gather v3: 8 dsts/wave, 8 feats/lane (16 B),
// each dst segment split into TWO interleaved streams (front/back half) ->
// 4 independent VMEM per iteration covering 16 edge-slots; iteration count
// = max over groups of ceil(len/2). Ragged handling: clamp + zero weight.
// ---------------------------------------------------------------------------
__global__ __launch_bounds__(256) void hop_kernel(
    const ushort* __restrict__ tin, ushort* __restrict__ tout,
    const uint2* __restrict__ csrE, const int* __restrict__ rowp)
{
    int w = (blockIdx.x * 256 + threadIdx.x) >> 6;
    if (w >= RR * (NN / 8)) return;
    int lane = threadIdx.x & 63;
    int g = lane >> 3;                 // dst group 0..7
    int f = (lane & 7) * 8;            // feature base 0..56
    int sh = ((lane >> 2) & 1) * 16;   // head select: f>=32 <=> bit2 of lane
    int r = w / (NN / 8);
    int n0 = (w - r * (NN / 8)) * 8;

    const int* rp = rowp + r * RPS + n0 + g;
    int bg = rp[0];
    int eg = rp[1];
    int len = eg - bg;
    int cl = (len + 1) >> 1;           // stream A length (ceil half)
    int b2 = bg + cl;                  // stream B start

    int m = cl;
    m = max(m, __shfl_xor(m, 8, 64));
    m = max(m, __shfl_xor(m, 16, 64));
    m = max(m, __shfl_xor(m, 32, 64));

    int lastA = bg + cl - 1;
    lastA = lastA > bg ? lastA : bg;
    lastA = lastA < (EE - 1) ? lastA : (EE - 1);
    int lastB = eg - 1;
    lastB = lastB > b2 ? lastB : b2;
    lastB = lastB < (EE - 1) ? lastB : (EE - 1);

    const ushort* T = tin + (size_t)r * NN * HD;
    const uint2* E = csrE + (size_t)r * EE;

    float accA[8] = {0.f, 0.f, 0.f, 0.f, 0.f, 0.f, 0.f, 0.f};
    float accB[8] = {0.f, 0.f, 0.f, 0.f, 0.f, 0.f, 0.f, 0.f};
    #pragma unroll 4
    for (int j = 0; j < m; j++) {
        int ia = bg + j;
        int iac = ia < lastA ? ia : lastA;
        int ib = b2 + j;
        int ibc = ib < lastB ? ib : lastB;
        uint2 ra = E[iac];
        uint2 rb = E[ibc];
        float wa = (j < cl) ? h2f((ushort)(ra.y >> sh)) : 0.f;
        float wb = (ib < eg) ? h2f((ushort)(rb.y >> sh)) : 0.f;
        uint4 ta = *(const uint4*)&T[(size_t)(ra.x & 0x7FFF) * HD + f];
        uint4 tb = *(const uint4*)&T[(size_t)(rb.x & 0x7FFF) * HD + f];
        float2 a0 = up2(ta.x), a1 = up2(ta.y), a2 = up2(ta.z), a3 = up2(ta.w);
        float2 b0 = up2(tb.x), b1 = up2(tb.y), b2v = up2(tb.z), b3 = up2(tb.w);
        accA[0] += wa * a0.x;  accA[1] += wa * a0.y;
        accA[2] += wa * a1.x;  accA[3] += wa * a1.y;
        accA[4] += wa * a2.x;  accA[5] += wa * a2.y;
        accA[6] += wa * a3.x;  accA[7] += wa * a3.y;
        accB[0] += wb * b0.x;  accB[1] += wb * b0.y;
        accB[2] += wb * b1.x;  accB[3] += wb * b1.y;
        accB[4] += wb * b2v.x; accB[5] += wb * b2v.y;
        accB[6] += wb * b3.x;  accB[7] += wb * b3.y;
    }
    ushort o[8];
    #pragma unroll
    for (int k = 0; k < 8; k++) o[k] = f2h(accA[k] + accB[k]);
    *(uint4*)&tout[((size_t)r * NN + n0 + g) * HD + f] = *(uint4*)o;
}

// ---------------------------------------------------------------------------
// K7: final — thread per (node, head), no LDS; head-mean fused via intra-wave
// shuffle (heads sit in adjacent lanes). Even lanes write out[n][0..31].
// ---------------------------------------------------------------------------
__global__ __launch_bounds__(256) void final_kernel(
    const ushort* __restrict__ t0, const ushort* __restrict__ t1,
    const ushort* __restrict__ t2, const ushort* __restrict__ t3,
    const float* __restrict__ res,
    const float* __restrict__ hal, const float* __restrict__ har,
    const float* __restrict__ w_rel, const float* __restrict__ b_rel,
    float* __restrict__ out)
{
    int idx = blockIdx.x * 256 + threadIdx.x;
    bool active = idx < NN * HH;
    int h_ = idx & 1;
    int n = idx >> 1;
    const ushort* tb[4] = {t0, t1, t2, t3};
    float o[DD];
    #pragma unroll
    for (int d = 0; d < DD; d++) o[d] = 0.f;

    if (active) {
        for (int r = 0; r < RR; r++) {
            float wr = b_rel[r];
            #pragma unroll
            for (int j = 0; j < RR; j++) wr += w_rel[r * RR + j];
            float halc[DD], harc[DD];
            const float4* hp = (const float4*)(hal + (r * HH + h_) * DD);
            const float4* gp = (const float4*)(har + (r * HH + h_) * DD);
            #pragma unroll
            for (int j = 0; j < 8; j++) {
                float4 a = hp[j];
                halc[4 * j] = a.x; halc[4 * j + 1] = a.y; halc[4 * j + 2] = a.z; halc[4 * j + 3] = a.w;
                float4 b = gp[j];
                harc[4 * j] = b.x; harc[4 * j + 1] = b.y; harc[4 * j + 2] = b.z; harc[4 * j + 3] = b.w;
            }
            size_t tbase = ((size_t)r * NN + n) * HD + h_ * DD;
            float sq[4], dl[4], dr = 0.f;
            #pragma unroll
            for (int k = 0; k < 4; k++) {
                const uint2* tp = (const uint2*)(tb[k] + tbase);
                float s = 0.f, d1 = 0.f;
                #pragma unroll
                for (int j = 0; j < 8; j++) {
                    uint2 q = tp[j];
                    float2 v0 = up2(q.x), v1 = up2(q.y);
                    s  += v0.x * v0.x + v0.y * v0.y + v1.x * v1.x + v1.y * v1.y;
                    d1 += v0.x * halc[4 * j] + v0.y * halc[4 * j + 1]
                        + v1.x * halc[4 * j + 2] + v1.y * halc[4 * j + 3];
                    if (k == 0)
                        dr += v0.x * harc[4 * j] + v0.y * harc[4 * j + 1]
                            + v1.x * harc[4 * j + 2] + v1.y * harc[4 * j + 3];
                }
                sq[k] = s; dl[k] = d1;
            }
            float inv[4], lg[4], mx = -1e30f;
            #pragma unroll
            for (int k = 0; k < 4; k++)
                inv[k] = 1.f / fmaxf(sqrtf(sq[k]), 1e-9f);
            #pragma unroll
            for (int k = 0; k < 4; k++) {
                float l = dl[k] * inv[k] + dr * inv[0];
                l = l > 0.f ? l : NEG * l;
                lg[k] = l;
                mx = fmaxf(mx, l);
            }
            float ssum = 0.f;
            #pragma unroll
            for (int k = 0; k < 4; k++) { lg[k] = __expf(lg[k] - mx); ssum += lg[k]; }
            float sw = wr / ssum;
            #pragma unroll
            for (int k = 0; k < 4; k++) {
                float coef = lg[k] * inv[k] * sw;
                const uint2* tp = (const uint2*)(tb[k] + tbase);
                #pragma unroll
                for (int j = 0; j < 8; j++) {
                    uint2 q = tp[j];
                    float2 v0 = up2(q.x), v1 = up2(q.y);
                    o[4 * j]     += coef * v0.x;
                    o[4 * j + 1] += coef * v0.y;
                    o[4 * j + 2] += coef * v1.x;
                    o[4 * j + 3] += coef * v1.y;
                }
            }
            const float4* rr = (const float4*)(res + ((size_t)r * NN + n) * HD + h_ * DD);
            #pragma unroll
            for (int j = 0; j < 8; j++) {
                float4 v = rr[j];
                o[4 * j]     += wr * v.x;
                o[4 * j + 1] += wr * v.y;
                o[4 * j + 2] += wr * v.z;
                o[4 * j + 3] += wr * v.w;
            }
        }
    }
    // head-mean: even lane (h=0) pulls odd lane's (h=1) values and writes out.
    float4* op = (float4*)(out + (size_t)n * DD);
    #pragma unroll
    for (int j = 0; j < 8; j++) {
        float x0 = o[4 * j],     x1 = o[4 * j + 1];
        float x2 = o[4 * j + 2], x3 = o[4 * j + 3];
        float y0 = __shfl_down(x0, 1, 64);
        float y1 = __shfl_down(x1, 1, 64);
        float y2 = __shfl_down(x2, 1, 64);
        float y3 = __shfl_down(x3, 1, 64);
        if (active && h_ == 0)
            op[j] = make_float4(0.5f * (x0 + y0), 0.5f * (x1 + y1),
                                0.5f * (x2 + y2), 0.5f * (x3 + y3));
    }
}

// ---------------------------------------------------------------------------
extern "C" void kernel_launch(void* const* d_in, const int* in_sizes, int n_in,
                              void* d_out, int out_size, void* d_ws, size_t ws_size,
                              hipStream_t stream) {
    (void)in_sizes; (void)n_in; (void)out_size; (void)ws_size;
    const float* h     = (const float*)d_in[0];
    const int*   src   = (const int*)d_in[1];
    const int*   dst   = (const int*)d_in[2];
    const float* fcw   = (const float*)d_in[3];
    const float* resw  = (const float*)d_in[4];
    const float* atl   = (const float*)d_in[5];
    const float* atr   = (const float*)d_in[6];
    const float* hal   = (const float*)d_in[7];
    const float* har   = (const float*)d_in[8];
    const float* wrel  = (const float*)d_in[9];
    const float* brel  = (const float*)d_in[10];
    float* out = (float*)d_out;

    float* ws = (float*)d_ws;
    size_t off = 0;
    float* res  = ws + off;  off += (size_t)RR * NN * HD;
    float* el   = ws + off;  off += (size_t)RR * NN * HH;
    float* er   = ws + off;  off += (size_t)RR * NN * HH;
    uint2* csrE = (uint2*)(ws + off);      off += (size_t)RR * EE * 2;
    unsigned* bucketRec = (unsigned*)(ws + off); off += (size_t)RR * EE;
    ushort* t0  = (ushort*)(ws + off);     off += (size_t)RR * NN * HD / 2;
    ushort* t1  = (ushort*)(ws + off);     off += (size_t)RR * NN * HD / 2;
    ushort* t2  = (ushort*)(ws + off);     off += (size_t)RR * NN * HD / 2;
    ushort* t3  = (ushort*)(ws + off);     off += (size_t)RR * NN * HD / 2;
    ushort* hb  = (ushort*)(ws + off);     off += (size_t)NN * IN / 2;
    ushort* wb  = (ushort*)(ws + off);     off += (size_t)RR * 128 * IN / 2;
    int* rowp   = (int*)(ws + off);  off += (size_t)RR * RPS;
    int* blkHist = (int*)(ws + off); off += (size_t)RR * NB * NBLK;
    int* bbase  = (int*)(ws + off);  off += (size_t)RR * (NB + 1);

    const int CVT_N = NN * IN / 4 + RR * 128 * IN;
    cvt_kernel<<<(CVT_N + 255) / 256, 256, 0, stream>>>(h, hb, fcw, resw, wb);
    proj_mfma<<<313 * RR, 256, 0, stream>>>(hb, wb, t0, res);
    attn_node_kernel<<<(RR * NN * HH + 255) / 256, 256, 0, stream>>>(t0, atl, atr, el, er);
    bhist_kernel<<<RR * NBLK, 256, 0, stream>>>(dst, blkHist);
    mscan_kernel<<<RR, 256, 0, stream>>>(blkHist, bbase);
    bscatter_kernel<<<RR * NBLK, 256, 0, stream>>>(src, dst, blkHist, bucketRec);
    bsort_alpha_kernel<<<RR * NB, 256, 0, stream>>>(bucketRec, bbase, el, er, csrE, rowp);
    hop_kernel<<<(RR * (NN / 8) + 3) / 4, 256, 0, stream>>>(t0, t1, csrE, rowp);
    hop_kernel<<<(RR * (NN / 8) + 3) / 4, 256, 0, stream>>>(t1, t2, csrE, rowp);
    hop_kernel<<<(RR * (NN / 8) + 3) / 4, 256, 0, stream>>>(t2, t3, csrE, rowp);
    final_kernel<<<(NN * HH + 255) / 256, 256, 0, stream>>>(t0, t1, t2, t3, res, hal, har, wrel, brel, out);
}

// Round 14
// 288.047 us; speedup vs baseline: 6.9559x; 1.0211x over previous
//
#include <hip/hip_runtime.h>
#include <hip/hip_bf16.h>

#define NN 20000
#define IN 128
#define HH 2
#define DD 32
#define HD 64
#define KK 3
#define RR 5
#define EE 320000
#define NEG 0.2f

#define PADK 136
#define NB 313     // buckets per relation (64 dsts each)
#define NBLK 64    // partition blocks per relation
#define CHUNK 5000 // EE / NBLK
#define CAP 2048   // max edges per bucket (mean 1024, sd ~32)
#define RPS 20004  // rowp row stride (NN+4, 16B-aligned rows; sentinel at [NN])

typedef short v8s __attribute__((ext_vector_type(8)));
typedef float v4f __attribute__((ext_vector_type(4)));

__device__ __forceinline__ ushort f2b(float f) {
    unsigned u = __float_as_uint(f);
    unsigned r = (u + 0x7fff + ((u >> 16) & 1)) >> 16;   // RNE
    return (ushort)r;
}
__device__ __forceinline__ ushort f2h(float f) {
    _Float16 h = (_Float16)f;
    return __builtin_bit_cast(ushort, h);
}
__device__ __forceinline__ float h2f(ushort u) {
    _Float16 h = __builtin_bit_cast(_Float16, u);
    return (float)h;
}
__device__ __forceinline__ float2 up2(unsigned u) {
    return make_float2(h2f((ushort)(u & 0xFFFF)), h2f((ushort)(u >> 16)));
}

// ---------------------------------------------------------------------------
// K0: weights -> wb bf16, transposed+fused: wb[r][col][k], col<64=fc else res
// (h conversion now fused into proj_mfma staging)
// ---------------------------------------------------------------------------
__global__ __launch_bounds__(256) void cvt_kernel(
    const float* __restrict__ fcw, const float* __restrict__ resw,
    ushort* __restrict__ wb)
{
    int j = blockIdx.x * 256 + threadIdx.x;
    if (j >= RR * 128 * IN) return;
    int k = j & 127;
    int c = (j >> 7) & 127;
    int r = j >> 14;
    float v = (c < HD) ? fcw[(r * IN + k) * HD + c] : resw[(r * IN + k) * HD + (c - HD)];
    wb[j] = f2b(v);
}

// ---------------------------------------------------------------------------
// K1: projection via bf16 MFMA; reads fp32 h directly (cvt in staging);
// emits fp16 table t0 (x) and fp16 res.
// ---------------------------------------------------------------------------
__global__ __launch_bounds__(256) void proj_mfma(
    const float* __restrict__ h, const ushort* __restrict__ wb,
    ushort* __restrict__ t0, ushort* __restrict__ resh)
{
    __shared__ ushort As[64 * PADK];
    __shared__ ushort Bs[128 * PADK];
    int bx = blockIdx.x;
    int r = bx / 313;
    int tile = bx - r * 313;
    int n0 = tile * 64;
    int tid = threadIdx.x;

    // stage A: 64 rows x 128 k, fp32 -> bf16. 2048 float4 chunks / 256 = 8 ea.
    #pragma unroll
    for (int i = 0; i < 8; i++) {
        int c = tid + 256 * i;
        int row = c >> 5;            // 32 float4 per row
        int off = (c & 31) * 4;
        int gn = n0 + row;
        float4 v = make_float4(0.f, 0.f, 0.f, 0.f);
        if (gn < NN) v = *(const float4*)&h[(size_t)gn * IN + off];
        *(ushort4*)&As[row * PADK + off] =
            make_ushort4(f2b(v.x), f2b(v.y), f2b(v.z), f2b(v.w));
    }
    const ushort* wr = wb + (size_t)r * 128 * IN;
    #pragma unroll
    for (int i = 0; i < 8; i++) {
        int c = tid + 256 * i;
        int row = c >> 4;
        int off = (c & 15) * 8;
        *(uint4*)&Bs[row * PADK + off] = *(const uint4*)&wr[row * IN + off];
    }
    __syncthreads();

    int w = tid >> 6, lane = tid & 63;
    int lm = lane & 15, lq = lane >> 4;

    v4f acc[4][2];
    #pragma unroll
    for (int mt = 0; mt < 4; mt++)
        #pragma unroll
        for (int nt = 0; nt < 2; nt++) acc[mt][nt] = (v4f){0.f, 0.f, 0.f, 0.f};

    const ushort* Ab = &As[lm * PADK + lq * 8];
    const ushort* Bb = &Bs[(w * 32 + lm) * PADK + lq * 8];

    #pragma unroll
    for (int ks = 0; ks < 4; ks++) {
        v8s a[4], b[2];
        #pragma unroll
        for (int mt = 0; mt < 4; mt++) a[mt] = *(const v8s*)(Ab + mt * 16 * PADK + ks * 32);
        #pragma unroll
        for (int nt = 0; nt < 2; nt++) b[nt] = *(const v8s*)(Bb + nt * 16 * PADK + ks * 32);
        #pragma unroll
        for (int mt = 0; mt < 4; mt++)
            #pragma unroll
            for (int nt = 0; nt < 2; nt++)
                acc[mt][nt] = __builtin_amdgcn_mfma_f32_16x16x32_bf16(a[mt], b[nt], acc[mt][nt], 0, 0, 0);
    }

    int colbase = w * 32 + lm;
    #pragma unroll
    for (int mt = 0; mt < 4; mt++) {
        #pragma unroll
        for (int nt = 0; nt < 2; nt++) {
            int col = colbase + nt * 16;
            #pragma unroll
            for (int p = 0; p < 4; p++) {
                int node = n0 + mt * 16 + lq * 4 + p;
                if (node < NN) {
                    float v = acc[mt][nt][p];
                    if (col < HD) {
                        t0[((size_t)r * NN + node) * HD + col] = f2h(v);
                    } else {
                        resh[((size_t)r * NN + node) * HD + (col - HD)] = f2h(v);
                    }
                }
            }
        }
    }
}

// ---------------------------------------------------------------------------
// K1b: per-node attention scalars el/er from fp16 t0
// ---------------------------------------------------------------------------
__global__ __launch_bounds__(256) void attn_node_kernel(
    const ushort* __restrict__ t0, const float* __restrict__ attn_l,
    const float* __restrict__ attn_r, float* __restrict__ el,
    float* __restrict__ er)
{
    int idx = blockIdx.x * 256 + threadIdx.x;
    if (idx >= RR * NN * HH) return;
    int h_ = idx & 1;
    int n = (idx >> 1) % NN;
    int r = idx / (NN * HH);
    const ushort* x = t0 + ((size_t)r * NN + n) * HD + h_ * DD;
    const float* al = attn_l + (r * HH + h_) * DD;
    const float* ar = attn_r + (r * HH + h_) * DD;
    uint4 p0 = *(const uint4*)(x);
    uint4 p1 = *(const uint4*)(x + 8);
    uint4 p2 = *(const uint4*)(x + 16);
    uint4 p3 = *(const uint4*)(x + 24);
    unsigned P[8] = {p0.x, p0.y, p0.z, p0.w, p1.x, p1.y, p1.z, p1.w};
    unsigned Q[8] = {p2.x, p2.y, p2.z, p2.w, p3.x, p3.y, p3.z, p3.w};
    float sl = 0.f, sr = 0.f;
    #pragma unroll
    for (int j = 0; j < 8; j++) {
        float2 v = up2(P[j]);
        sl += v.x * al[2 * j] + v.y * al[2 * j + 1];
        sr += v.x * ar[2 * j] + v.y * ar[2 * j + 1];
    }
    #pragma unroll
    for (int j = 0; j < 8; j++) {
        float2 v = up2(Q[j]);
        sl += v.x * al[16 + 2 * j] + v.y * al[16 + 2 * j + 1];
        sr += v.x * ar[16 + 2 * j] + v.y * ar[16 + 2 * j + 1];
    }
    el[idx] = sl;
    er[idx] = sr;
}

// ---------------------------------------------------------------------------
// A1: per-(relation, block) histogram of 313 buckets over a 5000-edge chunk.
// ---------------------------------------------------------------------------
__global__ __launch_bounds__(256) void bhist_kernel(
    const int* __restrict__ dst, int* __restrict__ blkHist)
{
    __shared__ int hh[NB];
    int r = blockIdx.x >> 6;
    int blk = blockIdx.x & 63;
    int tid = threadIdx.x;
    for (int i = tid; i < NB; i += 256) hh[i] = 0;
    __syncthreads();
    const int* D = dst + (size_t)r * EE + blk * CHUNK;
    for (int i = tid; i < CHUNK; i += 256)
        atomicAdd(&hh[D[i] >> 6], 1);
    __syncthreads();
    for (int i = tid; i < NB; i += 256)
        blkHist[((size_t)(r * NB + i)) * NBLK + blk] = hh[i];
}

// ---------------------------------------------------------------------------
// A2: per-relation exclusive scan over (bkt-major, blk-minor) matrix.
// ---------------------------------------------------------------------------
__global__ __launch_bounds__(256) void mscan_kernel(
    int* __restrict__ blkHist, int* __restrict__ bbase)
{
    __shared__ int wsum[4];
    __shared__ int carry;
    int r = blockIdx.x;
    int tid = threadIdx.x;
    int lane = tid & 63, w = tid >> 6;
    if (tid == 0) carry = 0;
    __syncthreads();
    int4* B4 = (int4*)(blkHist + (size_t)r * NB * NBLK);
    const int M4 = NB * NBLK / 4;   // 5008
    for (int base = 0; base < M4; base += 256) {
        int i4 = base + tid;
        int4 v = (i4 < M4) ? B4[i4] : make_int4(0, 0, 0, 0);
        int s = v.x + v.y + v.z + v.w;
        int x = s;
        #pragma unroll
        for (int off = 1; off < 64; off <<= 1) {
            int t = __shfl_up(x, off, 64);
            if (lane >= off) x += t;
        }
        if (lane == 63) wsum[w] = x;
        __syncthreads();
        int add = carry;
        for (int j = 0; j < w; j++) add += wsum[j];
        int px = add + x - s;
        if (i4 < M4) {
            int p0 = px, p1 = px + v.x, p2 = p1 + v.y, p3 = p2 + v.z;
            B4[i4] = make_int4(p0, p1, p2, p3);
            int e0 = i4 * 4;
            int pr[4] = {p0, p1, p2, p3};
            #pragma unroll
            for (int k = 0; k < 4; k++) {
                int e = e0 + k;
                if ((e & (NBLK - 1)) == 0) bbase[r * (NB + 1) + (e >> 6)] = pr[k];
            }
        }
        __syncthreads();
        if (tid == 255) carry += wsum[0] + wsum[1] + wsum[2] + wsum[3];
        __syncthreads();
    }
    if (tid == 0) bbase[r * (NB + 1) + NB] = EE;
}

// ---------------------------------------------------------------------------
// A3: partition scatter, LDS cursors only, exclusive global slot ranges.
// ---------------------------------------------------------------------------
__global__ __launch_bounds__(256) void bscatter_kernel(
    const int* __restrict__ src, const int* __restrict__ dst,
    const int* __restrict__ blkHist, unsigned* __restrict__ bucketRec)
{
    __shared__ int cur[NB];
    int r = blockIdx.x >> 6;
    int blk = blockIdx.x & 63;
    int tid = threadIdx.x;
    for (int i = tid; i < NB; i += 256)
        cur[i] = blkHist[((size_t)(r * NB + i)) * NBLK + blk];
    __syncthreads();
    const int* S = src + (size_t)r * EE + blk * CHUNK;
    const int* D = dst + (size_t)r * EE + blk * CHUNK;
    unsigned* BR = bucketRec + (size_t)r * EE;
    for (int i = tid; i < CHUNK; i += 256) {
        int s = S[i], d = D[i];
        int pos = atomicAdd(&cur[d >> 6], 1);
        BR[pos] = (unsigned)s | ((unsigned)(d & 63) << 15);
    }
}

// ---------------------------------------------------------------------------
// B: per-bucket LDS counting sort + exact per-dst softmax -> csrE records
// {src | dstLow<<15, half2(w0,w1)} + rowp (stride RPS), sequential writes.
// ---------------------------------------------------------------------------
__global__ __launch_bounds__(256) void bsort_alpha_kernel(
    const unsigned* __restrict__ bucketRec, const int* __restrict__ bbase,
    const float* __restrict__ el, const float* __restrict__ er,
    uint2* __restrict__ csrE, int* __restrict__ rowp)
{
    __shared__ int cnt64s[64];
    __shared__ int segS[65];
    __shared__ int cur[64];
    __shared__ float2 erL[64];
    __shared__ float2 mx2[64];
    __shared__ float2 inv2[64];
    __shared__ unsigned sSD[CAP];
    __shared__ float2 sL[CAP];

    int bk = blockIdx.x;
    int r = bk / NB;
    int bkt = bk - r * NB;
    int tid = threadIdx.x;
    int base = bbase[r * (NB + 1) + bkt];
    int cnt = bbase[r * (NB + 1) + bkt + 1] - base;
    if (cnt > CAP) cnt = CAP;

    if (tid < 64) {
        cnt64s[tid] = 0;
        int gn = bkt * 64 + tid;
        erL[tid] = (gn < NN) ? ((const float2*)er)[(size_t)r * NN + gn]
                             : make_float2(0.f, 0.f);
    }
    __syncthreads();
    const unsigned* BR = bucketRec + (size_t)r * EE + base;
    for (int i = tid; i < cnt; i += 256)
        atomicAdd(&cnt64s[(BR[i] >> 15) & 63], 1);
    __syncthreads();
    if (tid < 64) {
        int v = cnt64s[tid];
        int x = v;
        #pragma unroll
        for (int off = 1; off < 64; off <<= 1) {
            int tt = __shfl_up(x, off, 64);
            if (tid >= off) x += tt;
        }
        segS[tid] = x - v;
        cur[tid] = x - v;
        if (tid == 63) segS[64] = x;
    }
    __syncthreads();
    const float2* el2 = (const float2*)el + (size_t)r * NN;
    for (int i = tid; i < cnt; i += 256) {
        unsigned rec = BR[i];
        int s = rec & 0x7FFF;
        int d = (rec >> 15) & 63;
        float2 a = el2[s];
        float2 b = erL[d];
        float l0 = a.x + b.x; l0 = l0 > 0.f ? l0 : NEG * l0;
        float l1 = a.y + b.y; l1 = l1 > 0.f ? l1 : NEG * l1;
        int pos = atomicAdd(&cur[d], 1);
        sSD[pos] = rec;
        sL[pos] = make_float2(l0, l1);
    }
    __syncthreads();
    if (tid < 64) {
        int b0 = segS[tid], e0 = segS[tid + 1];
        float m0 = -1e30f, m1 = -1e30f;
        for (int i = b0; i < e0; i++) {
            float2 l = sL[i];
            m0 = fmaxf(m0, l.x); m1 = fmaxf(m1, l.y);
        }
        float s0 = 0.f, s1 = 0.f;
        for (int i = b0; i < e0; i++) {
            float2 l = sL[i];
            s0 += __expf(l.x - m0); s1 += __expf(l.y - m1);
        }
        mx2[tid] = make_float2(m0, m1);
        inv2[tid] = make_float2(1.f / fmaxf(s0, 1e-9f), 1.f / fmaxf(s1, 1e-9f));
        int gn = bkt * 64 + tid;
        if (gn < NN) rowp[r * RPS + gn] = base + segS[tid];
    }
    if (bkt == 0 && tid == 64) rowp[r * RPS + NN] = EE;
    __syncthreads();
    uint2* E = csrE + (size_t)r * EE + base;
    for (int i = tid; i < cnt; i += 256) {
        unsigned rec = sSD[i];
        int d = (rec >> 15) & 63;
        float2 l = sL[i];
        float w0 = __expf(l.x - mx2[d].x) * inv2[d].x;
        float w1 = __expf(l.y - mx2[d].y) * inv2[d].y;
        E[i] = make_uint2(rec, (unsigned)f2h(w0) | ((unsigned)f2h(w1) << 16));
    }
}

// ---------------------------------------------------------------------------
// K6: diffusion hop, PULL wide-gather v3: 8 dsts/wave, 8 feats/lane (16 B),
// each dst segment split into TWO interleaved streams (front/back half) ->
// 4 independent VMEM per iteration covering 16 edge-slots.
// ---------------------------------------------------------------------------
__global__ __launch_bounds__(256) void hop_kernel(
    const ushort* __restrict__ tin, ushort* __restrict__ tout,
    const uint2* __restrict__ csrE, const int* __restrict__ rowp)
{
    int w = (blockIdx.x * 256 + threadIdx.x) >> 6;
    if (w >= RR * (NN / 8)) return;
    int lane = threadIdx.x & 63;
    int g = lane >> 3;                 // dst group 0..7
    int f = (lane & 7) * 8;            // feature base 0..56
    int sh = ((lane >> 2) & 1) * 16;   // head select: f>=32 <=> bit2 of lane
    int r = w / (NN / 8);
    int n0 = (w - r * (NN / 8)) * 8;

    const int* rp = rowp + r * RPS + n0 + g;
    int bg = rp[0];
    int eg = rp[1];
    int len = eg - bg;
    int cl = (len + 1) >> 1;           // stream A length (ceil half)
    int b2 = bg + cl;                  // stream B start

    int m = cl;
    m = max(m, __shfl_xor(m, 8, 64));
    m = max(m, __shfl_xor(m, 16, 64));
    m = max(m, __shfl_xor(m, 32, 64));

    int lastA = bg + cl - 1;
    lastA = lastA > bg ? lastA : bg;
    lastA = lastA < (EE - 1) ? lastA : (EE - 1);
    int lastB = eg - 1;
    lastB = lastB > b2 ? lastB : b2;
    lastB = lastB < (EE - 1) ? lastB : (EE - 1);

    const ushort* T = tin + (size_t)r * NN * HD;
    const uint2* E = csrE + (size_t)r * EE;

    float accA[8] = {0.f, 0.f, 0.f, 0.f, 0.f, 0.f, 0.f, 0.f};
    float accB[8] = {0.f, 0.f, 0.f, 0.f, 0.f, 0.f, 0.f, 0.f};
    #pragma unroll 4
    for (int j = 0; j < m; j++) {
        int ia = bg + j;
        int iac = ia < lastA ? ia : lastA;
        int ib = b2 + j;
        int ibc = ib < lastB ? ib : lastB;
        uint2 ra = E[iac];
        uint2 rb = E[ibc];
        float wa = (j < cl) ? h2f((ushort)(ra.y >> sh)) : 0.f;
        float wb = (ib < eg) ? h2f((ushort)(rb.y >> sh)) : 0.f;
        uint4 ta = *(const uint4*)&T[(size_t)(ra.x & 0x7FFF) * HD + f];
        uint4 tb = *(const uint4*)&T[(size_t)(rb.x & 0x7FFF) * HD + f];
        float2 a0 = up2(ta.x), a1 = up2(ta.y), a2 = up2(ta.z), a3 = up2(ta.w);
        float2 b0 = up2(tb.x), b1 = up2(tb.y), b2v = up2(tb.z), b3 = up2(tb.w);
        accA[0] += wa * a0.x;  accA[1] += wa * a0.y;
        accA[2] += wa * a1.x;  accA[3] += wa * a1.y;
        accA[4] += wa * a2.x;  accA[5] += wa * a2.y;
        accA[6] += wa * a3.x;  accA[7] += wa * a3.y;
        accB[0] += wb * b0.x;  accB[1] += wb * b0.y;
        accB[2] += wb * b1.x;  accB[3] += wb * b1.y;
        accB[4] += wb * b2v.x; accB[5] += wb * b2v.y;
        accB[6] += wb * b3.x;  accB[7] += wb * b3.y;
    }
    ushort o[8];
    #pragma unroll
    for (int k = 0; k < 8; k++) o[k] = f2h(accA[k] + accB[k]);
    *(uint4*)&tout[((size_t)r * NN + n0 + g) * HD + f] = *(uint4*)o;
}

// ---------------------------------------------------------------------------
// K7: final — thread per (node, head); head-mean fused via intra-wave shuffle.
// res read as fp16.
// ---------------------------------------------------------------------------
__global__ __launch_bounds__(256) void final_kernel(
    const ushort* __restrict__ t0, const ushort* __restrict__ t1,
    const ushort* __restrict__ t2, const ushort* __restrict__ t3,
    const ushort* __restrict__ resh,
    const float* __restrict__ hal, const float* __restrict__ har,
    const float* __restrict__ w_rel, const float* __restrict__ b_rel,
    float* __restrict__ out)
{
    int idx = blockIdx.x * 256 + threadIdx.x;
    bool active = idx < NN * HH;
    int h_ = idx & 1;
    int n = idx >> 1;
    const ushort* tb[4] = {t0, t1, t2, t3};
    float o[DD];
    #pragma unroll
    for (int d = 0; d < DD; d++) o[d] = 0.f;

    if (active) {
        for (int r = 0; r < RR; r++) {
            float wr = b_rel[r];
            #pragma unroll
            for (int j = 0; j < RR; j++) wr += w_rel[r * RR + j];
            float halc[DD], harc[DD];
            const float4* hp = (const float4*)(hal + (r * HH + h_) * DD);
            const float4* gp = (const float4*)(har + (r * HH + h_) * DD);
            #pragma unroll
            for (int j = 0; j < 8; j++) {
                float4 a = hp[j];
                halc[4 * j] = a.x; halc[4 * j + 1] = a.y; halc[4 * j + 2] = a.z; halc[4 * j + 3] = a.w;
                float4 b = gp[j];
                harc[4 * j] = b.x; harc[4 * j + 1] = b.y; harc[4 * j + 2] = b.z; harc[4 * j + 3] = b.w;
            }
            size_t tbase = ((size_t)r * NN + n) * HD + h_ * DD;
            float sq[4], dl[4], dr = 0.f;
            #pragma unroll
            for (int k = 0; k < 4; k++) {
                const uint2* tp = (const uint2*)(tb[k] + tbase);
                float s = 0.f, d1 = 0.f;
                #pragma unroll
                for (int j = 0; j < 8; j++) {
                    uint2 q = tp[j];
                    float2 v0 = up2(q.x), v1 = up2(q.y);
                    s  += v0.x * v0.x + v0.y * v0.y + v1.x * v1.x + v1.y * v1.y;
                    d1 += v0.x * halc[4 * j] + v0.y * halc[4 * j + 1]
                        + v1.x * halc[4 * j + 2] + v1.y * halc[4 * j + 3];
                    if (k == 0)
                        dr += v0.x * harc[4 * j] + v0.y * harc[4 * j + 1]
                            + v1.x * harc[4 * j + 2] + v1.y * harc[4 * j + 3];
                }
                sq[k] = s; dl[k] = d1;
            }
            float inv[4], lg[4], mx = -1e30f;
            #pragma unroll
            for (int k = 0; k < 4; k++)
                inv[k] = 1.f / fmaxf(sqrtf(sq[k]), 1e-9f);
            #pragma unroll
            for (int k = 0; k < 4; k++) {
                float l = dl[k] * inv[k] + dr * inv[0];
                l = l > 0.f ? l : NEG * l;
                lg[k] = l;
                mx = fmaxf(mx, l);
            }
            float ssum = 0.f;
            #pragma unroll
            for (int k = 0; k < 4; k++) { lg[k] = __expf(lg[k] - mx); ssum += lg[k]; }
            float sw = wr / ssum;
            #pragma unroll
            for (int k = 0; k < 4; k++) {
                float coef = lg[k] * inv[k] * sw;
                const uint2* tp = (const uint2*)(tb[k] + tbase);
                #pragma unroll
                for (int j = 0; j < 8; j++) {
                    uint2 q = tp[j];
                    float2 v0 = up2(q.x), v1 = up2(q.y);
                    o[4 * j]     += coef * v0.x;
                    o[4 * j + 1] += coef * v0.y;
                    o[4 * j + 2] += coef * v1.x;
                    o[4 * j + 3] += coef * v1.y;
                }
            }
            const uint2* rr = (const uint2*)(resh + ((size_t)r * NN + n) * HD + h_ * DD);
            #pragma unroll
            for (int j = 0; j < 8; j++) {
                uint2 q = rr[j];
                float2 v0 = up2(q.x), v1 = up2(q.y);
                o[4 * j]     += wr * v0.x;
                o[4 * j + 1] += wr * v0.y;
                o[4 * j + 2] += wr * v1.x;
                o[4 * j + 3] += wr * v1.y;
            }
        }
    }
    // head-mean: even lane (h=0) pulls odd lane's (h=1) values and writes out.
    float4* op = (float4*)(out + (size_t)n * DD);
    #pragma unroll
    for (int j = 0; j < 8; j++) {
        float x0 = o[4 * j],     x1 = o[4 * j + 1];
        float x2 = o[4 * j + 2], x3 = o[4 * j + 3];
        float y0 = __shfl_down(x0, 1, 64);
        float y1 = __shfl_down(x1, 1, 64);
        float y2 = __shfl_down(x2, 1, 64);
        float y3 = __shfl_down(x3, 1, 64);
        if (active && h_ == 0)
            op[j] = make_float4(0.5f * (x0 + y0), 0.5f * (x1 + y1),
                                0.5f * (x2 + y2), 0.5f * (x3 + y3));
    }
}

// ---------------------------------------------------------------------------
extern "C" void kernel_launch(void* const* d_in, const int* in_sizes, int n_in,
                              void* d_out, int out_size, void* d_ws, size_t ws_size,
                              hipStream_t stream) {
    (void)in_sizes; (void)n_in; (void)out_size; (void)ws_size;
    const float* h     = (const float*)d_in[0];
    const int*   src   = (const int*)d_in[1];
    const int*   dst   = (const int*)d_in[2];
    const float* fcw   = (const float*)d_in[3];
    const float* resw  = (const float*)d_in[4];
    const float* atl   = (const float*)d_in[5];
    const float* atr   = (const float*)d_in[6];
    const float* hal   = (const float*)d_in[7];
    const float* har   = (const float*)d_in[8];
    const float* wrel  = (const float*)d_in[9];
    const float* brel  = (const float*)d_in[10];
    float* out = (float*)d_out;

    float* ws = (float*)d_ws;
    size_t off = 0;
    float* el   = ws + off;  off += (size_t)RR * NN * HH;
    float* er   = ws + off;  off += (size_t)RR * NN * HH;
    uint2* csrE = (uint2*)(ws + off);      off += (size_t)RR * EE * 2;
    unsigned* bucketRec = (unsigned*)(ws + off); off += (size_t)RR * EE;
    ushort* resh = (ushort*)(ws + off);    off += (size_t)RR * NN * HD / 2;
    ushort* t0  = (ushort*)(ws + off);     off += (size_t)RR * NN * HD / 2;
    ushort* t1  = (ushort*)(ws + off);     off += (size_t)RR * NN * HD / 2;
    ushort* t2  = (ushort*)(ws + off);     off += (size_t)RR * NN * HD / 2;
    ushort* t3  = (ushort*)(ws + off);     off += (size_t)RR * NN * HD / 2;
    ushort* wb  = (ushort*)(ws + off);     off += (size_t)RR * 128 * IN / 2;
    int* rowp   = (int*)(ws + off);  off += (size_t)RR * RPS;
    int* blkHist = (int*)(ws + off); off += (size_t)RR * NB * NBLK;
    int* bbase  = (int*)(ws + off);  off += (size_t)RR * (NB + 1);

    cvt_kernel<<<(RR * 128 * IN + 255) / 256, 256, 0, stream>>>(fcw, resw, wb);
    proj_mfma<<<313 * RR, 256, 0, stream>>>(h, wb, t0, resh);
    attn_node_kernel<<<(RR * NN * HH + 255) / 256, 256, 0, stream>>>(t0, atl, atr, el, er);
    bhist_kernel<<<RR * NBLK, 256, 0, stream>>>(dst, blkHist);
    mscan_kernel<<<RR, 256, 0, stream>>>(blkHist, bbase);
    bscatter_kernel<<<RR * NBLK, 256, 0, stream>>>(src, dst, blkHist, bucketRec);
    bsort_alpha_kernel<<<RR * NB, 256, 0, stream>>>(bucketRec, bbase, el, er, csrE, rowp);
    hop_kernel<<<(RR * (NN / 8) + 3) / 4, 256, 0, stream>>>(t0, t1, csrE, rowp);
    hop_kernel<<<(RR * (NN / 8) + 3) / 4, 256, 0, stream>>>(t1, t2, csrE, rowp);
    hop_kernel<<<(RR * (NN / 8) + 3) / 4, 256, 0, stream>>>(t2, t3, csrE, rowp);
    final_kernel<<<(NN * HH + 255) / 256, 256, 0, stream>>>(t0, t1, t2, t3, resh, hal, har, wrel, brel, out);
}